// Round 14
// baseline (306.955 us; speedup 1.0000x reference)
//
#include <hip/hip_runtime.h>
#include <math.h>

// R14: row-sliced, BARRIER-FREE restructure.
// Each wave owns 16 batch rows and computes the ENTIRE network for them
// (M = all 128 features, 8 m-tiles). All B-tiles are wave-private ->
// no cross-wave LDS sharing -> zero __syncthreads; every LDS round-trip is
// intra-wave (lgkmcnt only). ~2.5x less LDS traffic than the M-sliced R11/R12
// (which had all 4 waves redundantly reading the same 8KB B-tiles).
// Block = 4 independent waves (LDS co-allocation only), 12KB/wave.

typedef __attribute__((ext_vector_type(8))) short bf16x8;
typedef __attribute__((ext_vector_type(4))) float f32x4;
typedef __attribute__((ext_vector_type(8))) float f32x8;
typedef __attribute__((ext_vector_type(4))) __bf16 bf16x4f;
typedef __attribute__((ext_vector_type(8))) __bf16 bf16x8f;
typedef __attribute__((ext_vector_type(8))) unsigned short u16x8;

#define LROW 128   // shorts per LDS row

__device__ __forceinline__ float lrelu(float x){ return x > 0.f ? x : 0.01f * x; }

__device__ __forceinline__ unsigned short f2bf(float x){   // wprep only
    union { float f; unsigned u; } c; c.f = x;
    unsigned u = c.u; u += 0x7fffu + ((u >> 16) & 1u);
    return (unsigned short)(u >> 16);
}
__device__ __forceinline__ ushort4 pack4v(f32x4 v){
    union { bf16x4f b; ushort4 u; } c;
    c.b = __builtin_convertvector(v, bf16x4f);
    return c.u;
}
__device__ __forceinline__ u16x8 pack8v(f32x4 lo, f32x4 hi){
    f32x8 w;
    w[0]=lo[0]; w[1]=lo[1]; w[2]=lo[2]; w[3]=lo[3];
    w[4]=hi[0]; w[5]=hi[1]; w[6]=hi[2]; w[7]=hi[3];
    union { bf16x8f b; u16x8 u; } c;
    c.b = __builtin_convertvector(w, bf16x8f);
    return c.u;
}
__device__ __forceinline__ f32x4 ldg_nt4(const float* p){
    return __builtin_nontemporal_load((const f32x4*)p);
}

// swizzled LDS offset (shorts): 16B-slot XOR within each 8-row stripe
__device__ __forceinline__ int sw(int row, int col){
    return row * LROW + (col ^ ((row & 7) << 3));
}

// fragment-packed weight load: chunk (m-tile, kc) is 512 bf16 (1KB), lane-major.
__device__ __forceinline__ bf16x8 ldA(const unsigned short* __restrict__ WT, int Kc,
                                      int m0, int kc, int lane){
    return *(const bf16x8*)(WT + ((((size_t)(m0 >> 4)) * Kc + kc) << 9) + lane * 8);
}
// B-frag from a wave-private [16][128] bf16 tile
__device__ __forceinline__ bf16x8 ldB16(const unsigned short* L, int kc, int lane){
    int row = lane & 15;
    int col = kc * 32 + (lane >> 4) * 8;
    return *(const bf16x8*)(L + sw(row, col));
}
__device__ __forceinline__ void stB(unsigned short* L, int row, int col, ushort4 v){
    *(ushort4*)(L + sw(row, col)) = v;
}

// acc[8] += W^T (all 8 m-tiles) x B(wave-private LDS tile)
template<int NKC>
__device__ __forceinline__ void mm8(const unsigned short* __restrict__ WT, int Kc, int kc0,
                                    const unsigned short* Ls, int lane, f32x4 acc[8]){
#pragma unroll
    for (int kc = 0; kc < NKC; ++kc) {
        bf16x8 b = ldB16(Ls, kc, lane);
#pragma unroll
        for (int mt = 0; mt < 8; ++mt) {
            bf16x8 f = ldA(WT, Kc, mt * 16, kc0 + kc, lane);
            acc[mt] = __builtin_amdgcn_mfma_f32_16x16x32_bf16(f, b, acc[mt], 0, 0, 0);
        }
    }
}

// staging: wave loads its 16 rows x 128 cols (f32) into regs; n=-1 => s_i
// lane layout: row = lane>>2, 32-float segment = lane&3 (segs 0-2 from s, 3 from a)
__device__ __forceinline__ void ld_stage(const float* __restrict__ s,
                                         const float* __restrict__ a,
                                         int wrow0, int n, int lane, f32x4 R[8]){
    int lr = lane >> 2, seg = lane & 3;
    const float* p;
    if (seg < 3) p = s + (size_t)(wrow0 + lr) * 768 + (n < 0 ? 0 : 96 + 96 * n) + seg * 32;
    else         p = a + (size_t)(wrow0 + lr) * 256 + (n < 0 ? 0 : 32 + 32 * n);
#pragma unroll
    for (int j = 0; j < 8; ++j) R[j] = ldg_nt4(p + j * 4);
}
__device__ __forceinline__ void st_stage(unsigned short* stg, int lane, const f32x4 R[8]){
    int lr = lane >> 2, seg = lane & 3;
#pragma unroll
    for (int j = 0; j < 4; ++j)
        *(u16x8*)(stg + sw(lr, seg * 32 + j * 8)) = pack8v(R[2 * j], R[2 * j + 1]);
}

// destination offset of element (q=out_row, f=in_col) in fragment-packed layout
__device__ __forceinline__ int froff(int q, int f, int Kc){
    return (((q >> 4) * Kc + (f >> 5)) << 9) + (((f >> 3) & 3) << 7) + ((q & 15) << 3) + (f & 7);
}

// ---- weight prep: fp32 W[in][out] -> bf16 fragment-packed W^T in d_ws ----
__global__ void wprep(const float* __restrict__ Ws, const float* __restrict__ Wsa,
                      const float* __restrict__ Wq_, const float* __restrict__ Wk_,
                      const float* __restrict__ Wv_, const float* __restrict__ Wo_,
                      const float* __restrict__ W1, const float* __restrict__ W2,
                      unsigned short* __restrict__ o)
{
    int id = blockIdx.x * 256 + threadIdx.x;
    if (id >= 229376) return;
    float v; int dst;
    if (id < 12288)        { int q = id / 96, f = id - q * 96;
                             v = Ws[f * 128 + q];              dst = froff(q, f, 3); }
    else if (id < 126976)  { int li = id - 12288; int n = li >> 14; int r = li & 16383;
                             int q = r >> 7, f = r & 127;
                             v = Wsa[n * 16384 + f * 128 + q]; dst = 12288 + n * 16384 + froff(q, f, 4); }
    else if (id < 143360)  { int li = id - 126976; int q = li >> 7, f = li & 127;
                             v = Wq_[f * 128 + q];             dst = 126976 + froff(q, f, 4); }
    else if (id < 159744)  { int li = id - 143360; int q = li >> 7, f = li & 127;
                             v = Wk_[f * 128 + q];             dst = 143360 + froff(q, f, 4); }
    else if (id < 176128)  { int li = id - 159744; int q = li >> 7, f = li & 127;
                             v = Wv_[f * 128 + q];             dst = 159744 + froff(q, f, 4); }
    else if (id < 192512)  { int li = id - 176128; int q = li >> 7, f = li & 127;
                             v = Wo_[f * 128 + q];             dst = 176128 + froff(q, f, 4); }
    else if (id < 225280)  { int li = id - 192512; int q = li >> 8, f = li & 255;
                             v = W1[f * 128 + q];              dst = 192512 + froff(q, f, 8); }
    else                   { int li = id - 225280; int q = li >> 7, f = li & 127;
                             v = W2[f * 32 + q];               dst = 225280 + froff(q, f, 4); }
    o[dst] = f2bf(v);
}

__global__ void __launch_bounds__(256, 2)
ac_mfma(const float* __restrict__ s, const float* __restrict__ a,
        const unsigned short* __restrict__ WS,
        const float* __restrict__ b_enc_s, const float* __restrict__ b_enc_sa,
        const float* __restrict__ bv, const float* __restrict__ bo,
        const float* __restrict__ b_fc1, const float* __restrict__ b_fc2,
        float* __restrict__ out_q, float* __restrict__ out_allq)
{
    // 4 waves x 3 x [16][128] bf16 buffers = 48KB; wave-private slices
    __shared__ __align__(16) unsigned short SMEM[4 * 3 * 16 * LROW];

    const int t = threadIdx.x, lane = t & 63, wid = t >> 6;
    const int l15 = lane & 15, l4 = lane >> 4;
    const int wrow0 = blockIdx.x * 64 + wid * 16;
    const float rsd = 0.17677669529663687f;  // 1/sqrt(32)

    unsigned short* stg = SMEM + wid * 3 * 2048;        // staging / attn / h1
    unsigned short* eb  = stg + 2048;                   // e / ov ; stash overlay
    unsigned short* enc = stg + 4096;                   // s_enc (persists)

    const unsigned short* WencST = WS;
    const unsigned short* WsaT   = WS + 12288;
    const unsigned short* WqT    = WS + 126976;
    const unsigned short* WkT    = WS + 143360;
    const unsigned short* WvT    = WS + 159744;
    const unsigned short* WoT    = WS + 176128;
    const unsigned short* W1T    = WS + 192512;
    const unsigned short* W2T    = WS + 225280;

    f32x4 stgR[8];
    f32x4 acc[8];

    // ---- prologue: stage s_i, s_enc = lrelu(s_i @ Wenc_s + b) -> enc ----
    ld_stage(s, a, wrow0, -1, lane, stgR);
    st_stage(stg, lane, stgR);
#pragma unroll
    for (int mt = 0; mt < 8; ++mt) acc[mt] = (f32x4){0.f, 0.f, 0.f, 0.f};
    mm8<3>(WencST, 3, 0, stg, lane, acc);
    ld_stage(s, a, wrow0, 0, lane, stgR);      // issue agent-0 loads
#pragma unroll
    for (int mt = 0; mt < 8; ++mt) {
        float4 bb = *(const float4*)(b_enc_s + mt * 16 + l4 * 4);
        f32x4 v;
        v[0] = lrelu(acc[mt][0] + bb.x); v[1] = lrelu(acc[mt][1] + bb.y);
        v[2] = lrelu(acc[mt][2] + bb.z); v[3] = lrelu(acc[mt][3] + bb.w);
        stB(enc, l15, mt * 16 + l4 * 4, pack4v(v));
    }
    st_stage(stg, lane, stgR);                 // staging(0) (after enc-mm reads)

    // ---- Q = s_enc @ Wq (all 4 heads; register-resident) ----
    f32x4 q8[8];
#pragma unroll
    for (int mt = 0; mt < 8; ++mt) q8[mt] = (f32x4){0.f, 0.f, 0.f, 0.f};
    mm8<4>(WqT, 4, 0, enc, lane, q8);

    f32x4 atn[8];
#pragma unroll
    for (int mt = 0; mt < 8; ++mt) atn[mt] = (f32x4){0.f, 0.f, 0.f, 0.f};
    float m_[4] = {-INFINITY, -INFINITY, -INFINITY, -INFINITY};
    float l_[4] = {0.f, 0.f, 0.f, 0.f};

    // merged K+V + online softmax over the e-tile in eb (wave-private)
    auto kv_phase = [&](){
        f32x4 kk[8], vv[8];
#pragma unroll
        for (int mt = 0; mt < 8; ++mt) {
            kk[mt] = (f32x4){0.f, 0.f, 0.f, 0.f};
            vv[mt] = (f32x4){0.f, 0.f, 0.f, 0.f};
        }
#pragma unroll
        for (int kc = 0; kc < 4; ++kc) {
            bf16x8 b = ldB16(eb, kc, lane);
#pragma unroll
            for (int mt = 0; mt < 8; ++mt) {
                bf16x8 fk = ldA(WkT, 4, mt * 16, kc, lane);
                bf16x8 fv = ldA(WvT, 4, mt * 16, kc, lane);
                kk[mt] = __builtin_amdgcn_mfma_f32_16x16x32_bf16(fk, b, kk[mt], 0, 0, 0);
                vv[mt] = __builtin_amdgcn_mfma_f32_16x16x32_bf16(fv, b, vv[mt], 0, 0, 0);
            }
        }
        float pr[4], corr[4];
#pragma unroll
        for (int h = 0; h < 4; ++h) {
            float p = 0.f;
#pragma unroll
            for (int mi = 0; mi < 2; ++mi) {
                int mt = 2 * h + mi;
#pragma unroll
                for (int r = 0; r < 4; ++r) p = fmaf(q8[mt][r], kk[mt][r], p);
            }
            p += __shfl_xor(p, 16);
            p += __shfl_xor(p, 32);
            float sc = p * rsd;
            float mo = m_[h], mn = fmaxf(mo, sc);
            pr[h]   = __expf(sc - mn);
            corr[h] = __expf(mo - mn);
            l_[h] = l_[h] * corr[h] + pr[h];
            m_[h] = mn;
        }
#pragma unroll
        for (int mt = 0; mt < 8; ++mt) {
            int h = mt >> 1;
            float4 bb = *(const float4*)(bv + mt * 16 + l4 * 4);
#pragma unroll
            for (int r = 0; r < 4; ++r) {
                float vx = lrelu(vv[mt][r] + ((const float*)&bb)[r]);
                atn[mt][r] = fmaf(atn[mt][r], corr[h], pr[h] * vx);
            }
        }
    };

    // ---- agent loop: NO barriers; single stg + single eb, wave-serial ----
    for (int n = 0; n < 7; ++n) {
        if (n < 6) ld_stage(s, a, wrow0, n + 1, lane, stgR);  // issue next loads
        if (n) kv_phase();                                    // K/V(n-1) from eb

        // e(n) = lrelu(sa(n) @ Wsa[n] + b)   (reads stg = staging(n))
#pragma unroll
        for (int mt = 0; mt < 8; ++mt) acc[mt] = (f32x4){0.f, 0.f, 0.f, 0.f};
        mm8<4>(WsaT + n * 16384, 4, 0, stg, lane, acc);
#pragma unroll
        for (int mt = 0; mt < 8; ++mt) {
            float4 bb = *(const float4*)(b_enc_sa + n * 128 + mt * 16 + l4 * 4);
            f32x4 v;
            v[0] = lrelu(acc[mt][0] + bb.x); v[1] = lrelu(acc[mt][1] + bb.y);
            v[2] = lrelu(acc[mt][2] + bb.z); v[3] = lrelu(acc[mt][3] + bb.w);
            stB(eb, l15, mt * 16 + l4 * 4, pack4v(v));        // overwrites e(n-1) AFTER kv read it
        }
        if (n < 6) st_stage(stg, lane, stgR);                 // staging(n+1) after e-mm reads
    }
    kv_phase();                                               // agent 6

    // ---- attn normalize -> stg ----
#pragma unroll
    for (int mt = 0; mt < 8; ++mt) {
        float inv = 1.f / l_[mt >> 1];
        f32x4 v;
        v[0] = atn[mt][0] * inv; v[1] = atn[mt][1] * inv;
        v[2] = atn[mt][2] * inv; v[3] = atn[mt][3] * inv;
        stB(stg, l15, mt * 16 + l4 * 4, pack4v(v));
    }

    // ---- ov = attn @ Wo + bo -> eb ----
#pragma unroll
    for (int mt = 0; mt < 8; ++mt) acc[mt] = (f32x4){0.f, 0.f, 0.f, 0.f};
    mm8<4>(WoT, 4, 0, stg, lane, acc);
#pragma unroll
    for (int mt = 0; mt < 8; ++mt) {
        float4 bb = *(const float4*)(bo + mt * 16 + l4 * 4);
        f32x4 v;
        v[0] = acc[mt][0] + bb.x; v[1] = acc[mt][1] + bb.y;
        v[2] = acc[mt][2] + bb.z; v[3] = acc[mt][3] + bb.w;
        stB(eb, l15, mt * 16 + l4 * 4, pack4v(v));
    }

    // ---- h1 = lrelu([s_enc | ov] @ W_fc1 + b1) -> stg ----
#pragma unroll
    for (int mt = 0; mt < 8; ++mt) acc[mt] = (f32x4){0.f, 0.f, 0.f, 0.f};
    mm8<4>(W1T, 8, 0, enc, lane, acc);   // k = 0..127
    mm8<4>(W1T, 8, 4, eb, lane, acc);    // k = 128..255
#pragma unroll
    for (int mt = 0; mt < 8; ++mt) {
        float4 bb = *(const float4*)(b_fc1 + mt * 16 + l4 * 4);
        f32x4 v;
        v[0] = lrelu(acc[mt][0] + bb.x); v[1] = lrelu(acc[mt][1] + bb.y);
        v[2] = lrelu(acc[mt][2] + bb.z); v[3] = lrelu(acc[mt][3] + bb.w);
        stB(stg, l15, mt * 16 + l4 * 4, pack4v(v));
    }

    // ---- all_q = h1 @ W_fc2 + b2 (2 m-tiles), store + stash ----
    float* stashF = (float*)enc;         // enc dead after h1-mm
    {
        f32x4 aq[2];
        aq[0] = (f32x4){0.f, 0.f, 0.f, 0.f};
        aq[1] = (f32x4){0.f, 0.f, 0.f, 0.f};
#pragma unroll
        for (int kc = 0; kc < 4; ++kc) {
            bf16x8 b = ldB16(stg, kc, lane);
#pragma unroll
            for (int mt = 0; mt < 2; ++mt) {
                bf16x8 f = ldA(W2T, 4, mt * 16, kc, lane);
                aq[mt] = __builtin_amdgcn_mfma_f32_16x16x32_bf16(f, b, aq[mt], 0, 0, 0);
            }
        }
#pragma unroll
        for (int mt = 0; mt < 2; ++mt) {
            float4 bb = *(const float4*)(b_fc2 + mt * 16 + l4 * 4);
            f32x4 v;
            v[0] = aq[mt][0] + bb.x; v[1] = aq[mt][1] + bb.y;
            v[2] = aq[mt][2] + bb.z; v[3] = aq[mt][3] + bb.w;
            *(f32x4*)(out_allq + (size_t)(wrow0 + l15) * 32 + mt * 16 + l4 * 4) = v;
            *(f32x4*)(stashF + l15 * 36 + mt * 16 + l4 * 4) = v;
        }
    }

    // ---- q = all_q[argmax(a[:, :32])] : lanes 0..15 handle the wave's rows ----
    if (lane < 16) {
        int row = wrow0 + lane;
        float best = -INFINITY; int bi = 0;
#pragma unroll
        for (int jj = 0; jj < 8; ++jj) {
            f32x4 v = ldg_nt4(a + (size_t)row * 256 + jj * 4);
#pragma unroll
            for (int e2 = 0; e2 < 4; ++e2)
                if (v[e2] > best) { best = v[e2]; bi = jj * 4 + e2; }
        }
        out_q[row] = stashF[lane * 36 + bi];
    }
}

extern "C" void kernel_launch(void* const* d_in, const int* in_sizes, int n_in,
                              void* d_out, int out_size, void* d_ws, size_t ws_size,
                              hipStream_t stream)
{
    (void)n_in; (void)out_size; (void)ws_size;
    const float* s        = (const float*)d_in[0];
    const float* a        = (const float*)d_in[1];
    const float* W_enc_s  = (const float*)d_in[2];
    const float* b_enc_s  = (const float*)d_in[3];
    const float* W_enc_sa = (const float*)d_in[4];
    const float* b_enc_sa = (const float*)d_in[5];
    const float* Wq       = (const float*)d_in[6];
    const float* Wk       = (const float*)d_in[7];
    const float* Wv       = (const float*)d_in[8];
    const float* bv       = (const float*)d_in[9];
    const float* Wo       = (const float*)d_in[10];
    const float* bo       = (const float*)d_in[11];
    const float* W_fc1    = (const float*)d_in[12];
    const float* b_fc1    = (const float*)d_in[13];
    const float* W_fc2    = (const float*)d_in[14];
    const float* b_fc2    = (const float*)d_in[15];

    int B = in_sizes[0] / 768;
    float* out_q    = (float*)d_out;
    float* out_allq = out_q + B;
    unsigned short* WS = (unsigned short*)d_ws;

    wprep<<<dim3(896), dim3(256), 0, stream>>>(W_enc_s, W_enc_sa, Wq, Wk, Wv, Wo,
                                               W_fc1, W_fc2, WS);
    ac_mfma<<<dim3(B / 64), dim3(256), 0, stream>>>(s, a, WS, b_enc_s, b_enc_sa,
                                                    bv, bo, b_fc1, b_fc2,
                                                    out_q, out_allq);
}

// Round 15
// 144.713 us; speedup vs baseline: 2.1211x; 2.1211x over previous
//
#include <hip/hip_runtime.h>
#include <math.h>

// R15 = R11/R12 structure (best, 65.3us) scaled to TRB=64 with nt=4 per wave:
// same per-wave M-slice (32 feats) so register state stays bounded, but each
// weight-fragment stream (Wsa/Wk/Wv: ~96KB/iter/block from L2) now serves 64
// rows instead of 32 -> per-row weight traffic halves (the measured ~9k-cycle
// iteration wall is L2 fragment bandwidth). 64 kv-MFMAs/wave/iter.
// R14 lesson re-confirmed: never give one wave all 8 m-tiles (reg blowup).

typedef __attribute__((ext_vector_type(8))) short bf16x8;
typedef __attribute__((ext_vector_type(4))) float f32x4;
typedef __attribute__((ext_vector_type(4))) __bf16 bf16x4f;

#define LROW 128   // shorts per LDS row (swizzled, no pad)
#define TRB 64

__device__ __forceinline__ float lrelu(float x){ return x > 0.f ? x : 0.01f * x; }

__device__ __forceinline__ unsigned short f2bf(float x){   // wprep only
    union { float f; unsigned u; } c; c.f = x;
    unsigned u = c.u; u += 0x7fffu + ((u >> 16) & 1u);
    return (unsigned short)(u >> 16);
}
__device__ __forceinline__ ushort4 pack4v(f32x4 v){
    union { bf16x4f b; ushort4 u; } c;
    c.b = __builtin_convertvector(v, bf16x4f);   // 2x v_cvt_pk_bf16_f32
    return c.u;
}
__device__ __forceinline__ f32x4 ldg_nt4(const float* p){
    return __builtin_nontemporal_load((const f32x4*)p);
}

// swizzled LDS offset (shorts): 16B-slot XOR within each 8-row stripe
__device__ __forceinline__ int sw(int row, int col){
    return row * LROW + (col ^ ((row & 7) << 3));
}

// fragment-packed weight load: chunk (m-tile, kc) is 512 bf16 (1KB), lane-major.
__device__ __forceinline__ bf16x8 ldA(const unsigned short* __restrict__ WT, int Kc,
                                      int m0, int kc, int lane){
    return *(const bf16x8*)(WT + ((((size_t)(m0 >> 4)) * Kc + kc) << 9) + lane * 8);
}
__device__ __forceinline__ bf16x8 ldB(const unsigned short* L, int n0, int kc, int lane){
    int row = n0 + (lane & 15);
    int col = kc * 32 + (lane >> 4) * 8;
    return *(const bf16x8*)(L + sw(row, col));
}
__device__ __forceinline__ void stB(unsigned short* L, int row, int col, ushort4 v){
    *(ushort4*)(L + sw(row, col)) = v;
}

template<int NKC>
__device__ __forceinline__ void ldW(const unsigned short* __restrict__ WT, int Kc, int M0,
                                    int kc0, int lane, bf16x8 F[2][NKC]){
#pragma unroll
    for (int mt = 0; mt < 2; ++mt)
#pragma unroll
        for (int kc = 0; kc < NKC; ++kc)
            F[mt][kc] = ldA(WT, Kc, M0 + mt * 16, kc0 + kc, lane);
}

// acc[2][4] += F(regs) x B(LDS, 4 n-tiles = 64 rows)
template<int NKC>
__device__ __forceinline__ void mmR(const bf16x8 F[2][NKC], const unsigned short* Ls,
                                    int lane, f32x4 acc[2][4]){
#pragma unroll
    for (int kc = 0; kc < NKC; ++kc) {
        bf16x8 b[4];
#pragma unroll
        for (int nt = 0; nt < 4; ++nt) b[nt] = ldB(Ls, nt * 16, kc, lane);
#pragma unroll
        for (int mt = 0; mt < 2; ++mt)
#pragma unroll
            for (int nt = 0; nt < 4; ++nt)
                acc[mt][nt] = __builtin_amdgcn_mfma_f32_16x16x32_bf16(F[mt][kc], b[nt], acc[mt][nt], 0, 0, 0);
    }
}

template<int NKC>
__device__ __forceinline__ void mmG(const unsigned short* __restrict__ WT, int Kc, int M0,
                                    int kc0, const unsigned short* Ls, int lane,
                                    f32x4 acc[2][4]){
    bf16x8 F[2][NKC];
    ldW<NKC>(WT, Kc, M0, kc0, lane, F);
    mmR<NKC>(F, Ls, lane, acc);
}

// staging loads (non-temporal, f32 in regs); n = -1 => s_i (a-part lands unused)
__device__ __forceinline__ void ld_sa_f(const float* __restrict__ s, const float* __restrict__ a,
                                        int row0, int n, int t, f32x4 sf[6], f32x4 af[2]){
#pragma unroll
    for (int i = 0; i < 6; ++i) {
        int idx = t + 256 * i; int r = idx / 24, c4 = idx % 24;
        sf[i] = ldg_nt4(s + (size_t)(row0 + r) * 768 + 96 + 96 * n + c4 * 4);
    }
#pragma unroll
    for (int i = 0; i < 2; ++i) {
        int idx = t + 256 * i; int r = idx >> 3, c4 = idx & 7;
        af[i] = ldg_nt4(a + (size_t)(row0 + r) * 256 + 32 + 32 * n + c4 * 4);
    }
}
__device__ __forceinline__ void st_sa(unsigned short* buf, int t,
                                      const f32x4 sf[6], const f32x4 af[2]){
#pragma unroll
    for (int i = 0; i < 6; ++i) {
        int idx = t + 256 * i; int r = idx / 24, c4 = idx % 24;
        stB(buf, r, c4 * 4, pack4v(sf[i]));
    }
#pragma unroll
    for (int i = 0; i < 2; ++i) {
        int idx = t + 256 * i; int r = idx >> 3, c4 = idx & 7;
        stB(buf, r, 96 + c4 * 4, pack4v(af[i]));
    }
}

// destination offset of element (q=out_row, f=in_col) in fragment-packed layout
__device__ __forceinline__ int froff(int q, int f, int Kc){
    return (((q >> 4) * Kc + (f >> 5)) << 9) + (((f >> 3) & 3) << 7) + ((q & 15) << 3) + (f & 7);
}

// ---- weight prep: fp32 W[in][out] -> bf16 fragment-packed W^T in d_ws ----
__global__ void wprep(const float* __restrict__ Ws, const float* __restrict__ Wsa,
                      const float* __restrict__ Wq_, const float* __restrict__ Wk_,
                      const float* __restrict__ Wv_, const float* __restrict__ Wo_,
                      const float* __restrict__ W1, const float* __restrict__ W2,
                      unsigned short* __restrict__ o)
{
    int id = blockIdx.x * 256 + threadIdx.x;
    if (id >= 229376) return;
    float v; int dst;
    if (id < 12288)        { int q = id / 96, f = id - q * 96;
                             v = Ws[f * 128 + q];              dst = froff(q, f, 3); }
    else if (id < 126976)  { int li = id - 12288; int n = li >> 14; int r = li & 16383;
                             int q = r >> 7, f = r & 127;
                             v = Wsa[n * 16384 + f * 128 + q]; dst = 12288 + n * 16384 + froff(q, f, 4); }
    else if (id < 143360)  { int li = id - 126976; int q = li >> 7, f = li & 127;
                             v = Wq_[f * 128 + q];             dst = 126976 + froff(q, f, 4); }
    else if (id < 159744)  { int li = id - 143360; int q = li >> 7, f = li & 127;
                             v = Wk_[f * 128 + q];             dst = 143360 + froff(q, f, 4); }
    else if (id < 176128)  { int li = id - 159744; int q = li >> 7, f = li & 127;
                             v = Wv_[f * 128 + q];             dst = 159744 + froff(q, f, 4); }
    else if (id < 192512)  { int li = id - 176128; int q = li >> 7, f = li & 127;
                             v = Wo_[f * 128 + q];             dst = 176128 + froff(q, f, 4); }
    else if (id < 225280)  { int li = id - 192512; int q = li >> 8, f = li & 255;
                             v = W1[f * 128 + q];              dst = 192512 + froff(q, f, 8); }
    else                   { int li = id - 225280; int q = li >> 7, f = li & 127;
                             v = W2[f * 32 + q];               dst = 225280 + froff(q, f, 4); }
    o[dst] = f2bf(v);
}

__global__ void __launch_bounds__(256, 2)
ac_mfma(const float* __restrict__ s, const float* __restrict__ a,
        const unsigned short* __restrict__ WS,
        const float* __restrict__ b_enc_s, const float* __restrict__ b_enc_sa,
        const float* __restrict__ bv, const float* __restrict__ bo,
        const float* __restrict__ b_fc1, const float* __restrict__ b_fc2,
        float* __restrict__ out_q, float* __restrict__ out_allq)
{
    // 5 x [64][128] bf16 = 80KB -> 2 blocks/CU by LDS
    __shared__ __align__(16) unsigned short SMEM[5 * TRB * LROW];
    unsigned short* bufA0 = SMEM;                     // staging even / attn / h1
    unsigned short* bufA1 = SMEM + TRB * LROW;        // staging odd ; S-overlay
    unsigned short* sE0   = SMEM + 2 * TRB * LROW;    // e(even) / ov ; P-overlay
    unsigned short* sE1   = SMEM + 3 * TRB * LROW;    // e(odd)       ; P-overlay
    unsigned short* sENC  = SMEM + 4 * TRB * LROW;    // s_enc

    const int t = threadIdx.x, lane = t & 63, wid = t >> 6;
    const int l15 = lane & 15, l4 = lane >> 4;
    const int M0 = 32 * wid;
    const int row0 = blockIdx.x * TRB;
    const float rsd = 0.17677669529663687f;  // 1/sqrt(32)

    const unsigned short* WencST = WS;
    const unsigned short* WsaT   = WS + 12288;
    const unsigned short* WqT    = WS + 126976;
    const unsigned short* WkT    = WS + 143360;
    const unsigned short* WvT    = WS + 159744;
    const unsigned short* WoT    = WS + 176128;
    const unsigned short* W1T    = WS + 192512;
    const unsigned short* W2T    = WS + 225280;

    f32x4 sf[6]; f32x4 af[2];

    // ---- prologue: stage s_i -> bufA0 ----
    ld_sa_f(s, a, row0, -1, t, sf, af);
    st_sa(bufA0, t, sf, af);
    __syncthreads();                            // P1

    // ---- s_enc = lrelu(s_i @ Wenc_s + b) ----
    f32x4 acc[2][4];
#pragma unroll
    for (int mt = 0; mt < 2; ++mt)
#pragma unroll
        for (int nt = 0; nt < 4; ++nt) acc[mt][nt] = (f32x4){0.f, 0.f, 0.f, 0.f};
    mmG<3>(WencST, 3, M0, 0, bufA0, lane, acc);
    ld_sa_f(s, a, row0, 0, t, sf, af);          // issue agent-0 staging loads
    __syncthreads();                            // P2: enc reads of bufA0 done
#pragma unroll
    for (int mt = 0; mt < 2; ++mt) {
        float4 bb = *(const float4*)(b_enc_s + M0 + mt * 16 + l4 * 4);
#pragma unroll
        for (int nt = 0; nt < 4; ++nt) {
            f32x4 v;
            v[0] = lrelu(acc[mt][nt][0] + bb.x); v[1] = lrelu(acc[mt][nt][1] + bb.y);
            v[2] = lrelu(acc[mt][nt][2] + bb.z); v[3] = lrelu(acc[mt][nt][3] + bb.w);
            stB(sENC, nt * 16 + l15, M0 + mt * 16 + l4 * 4, pack4v(v));
        }
    }
    st_sa(bufA1, t, sf, af);                    // staging(0) -> bufA1
    __syncthreads();                            // P3: sENC + staging(0) visible

    // ---- Q (register-resident; wave wid == head wid) ----
    f32x4 q[2][4];
#pragma unroll
    for (int mt = 0; mt < 2; ++mt)
#pragma unroll
        for (int nt = 0; nt < 4; ++nt) q[mt][nt] = (f32x4){0.f, 0.f, 0.f, 0.f};
    mmG<4>(WqT, 4, M0, 0, sENC, lane, q);

    float4 bvf[2];
#pragma unroll
    for (int mt = 0; mt < 2; ++mt) bvf[mt] = *(const float4*)(bv + M0 + mt * 16 + l4 * 4);

    f32x4 atn[2][4];
#pragma unroll
    for (int mt = 0; mt < 2; ++mt)
#pragma unroll
        for (int nt = 0; nt < 4; ++nt) atn[mt][nt] = (f32x4){0.f, 0.f, 0.f, 0.f};
    float m_[4] = {-INFINITY, -INFINITY, -INFINITY, -INFINITY};
    float l_[4] = {0.f, 0.f, 0.f, 0.f};

    // merged K+V + online-softmax for one e-tile (single pass over EB)
    auto kv_phase = [&](const unsigned short* EB){
        f32x4 kk[2][4], vv[2][4];
#pragma unroll
        for (int mt = 0; mt < 2; ++mt)
#pragma unroll
            for (int nt = 0; nt < 4; ++nt) {
                kk[mt][nt] = (f32x4){0.f, 0.f, 0.f, 0.f};
                vv[mt][nt] = (f32x4){0.f, 0.f, 0.f, 0.f};
            }
#pragma unroll
        for (int kc = 0; kc < 4; ++kc) {
            bf16x8 b[4];
#pragma unroll
            for (int nt = 0; nt < 4; ++nt) b[nt] = ldB(EB, nt * 16, kc, lane);
#pragma unroll
            for (int mt = 0; mt < 2; ++mt) {
                bf16x8 fk = ldA(WkT, 4, M0 + mt * 16, kc, lane);
                bf16x8 fv = ldA(WvT, 4, M0 + mt * 16, kc, lane);
#pragma unroll
                for (int nt = 0; nt < 4; ++nt) {
                    kk[mt][nt] = __builtin_amdgcn_mfma_f32_16x16x32_bf16(fk, b[nt], kk[mt][nt], 0, 0, 0);
                    vv[mt][nt] = __builtin_amdgcn_mfma_f32_16x16x32_bf16(fv, b[nt], vv[mt][nt], 0, 0, 0);
                }
            }
        }
        float pr[4], corr[4];
#pragma unroll
        for (int nt = 0; nt < 4; ++nt) {
            float p = 0.f;
#pragma unroll
            for (int mt = 0; mt < 2; ++mt)
#pragma unroll
                for (int r = 0; r < 4; ++r) p = fmaf(q[mt][nt][r], kk[mt][nt][r], p);
            p += __shfl_xor(p, 16);
            p += __shfl_xor(p, 32);
            float sc = p * rsd;
            float mo = m_[nt], mn = fmaxf(mo, sc);
            pr[nt]   = __expf(sc - mn);
            corr[nt] = __expf(mo - mn);
            l_[nt] = l_[nt] * corr[nt] + pr[nt];
            m_[nt] = mn;
        }
#pragma unroll
        for (int mt = 0; mt < 2; ++mt)
#pragma unroll
            for (int nt = 0; nt < 4; ++nt)
#pragma unroll
                for (int r = 0; r < 4; ++r) {
                    float vx = lrelu(vv[mt][nt][r] + ((const float*)&bvf[mt])[r]);
                    atn[mt][nt][r] = fmaf(atn[mt][nt][r], corr[nt], pr[nt] * vx);
                }
    };

    // ---- agent loop: ONE barrier per iteration ----
    for (int n = 0; n < 7; ++n) {
        unsigned short* stageRd = (n & 1) ? bufA0 : bufA1;
        unsigned short* stageWr = (n & 1) ? bufA1 : bufA0;
        unsigned short* eWr     = (n & 1) ? sE1 : sE0;
        unsigned short* eRd     = (n & 1) ? sE0 : sE1;

        if (n < 6) ld_sa_f(s, a, row0, n + 1, t, sf, af);   // issue nt loads early
        bf16x8 F[2][4];
        ldW<4>(WsaT + n * 16384, 4, M0, 0, lane, F);        // issue Wsa(n) frags

        if (n) kv_phase(eRd);                               // KV(n-1) under the loads

        f32x4 e[2][4];
#pragma unroll
        for (int mt = 0; mt < 2; ++mt)
#pragma unroll
            for (int nt = 0; nt < 4; ++nt) e[mt][nt] = (f32x4){0.f, 0.f, 0.f, 0.f};
        mmR<4>(F, stageRd, lane, e);

#pragma unroll
        for (int mt = 0; mt < 2; ++mt) {
            float4 bb = *(const float4*)(b_enc_sa + n * 128 + M0 + mt * 16 + l4 * 4);
#pragma unroll
            for (int nt = 0; nt < 4; ++nt) {
                f32x4 v;
                v[0] = lrelu(e[mt][nt][0] + bb.x); v[1] = lrelu(e[mt][nt][1] + bb.y);
                v[2] = lrelu(e[mt][nt][2] + bb.z); v[3] = lrelu(e[mt][nt][3] + bb.w);
                stB(eWr, nt * 16 + l15, M0 + mt * 16 + l4 * 4, pack4v(v));
            }
        }
        if (n < 6) st_sa(stageWr, t, sf, af);
        __syncthreads();                        // the one barrier
    }
    kv_phase(sE0);                              // agent 6 (e(6) is in sE0)

    // ---- attn normalize -> bufA0 ----
#pragma unroll
    for (int mt = 0; mt < 2; ++mt)
#pragma unroll
        for (int nt = 0; nt < 4; ++nt) {
            float inv = 1.f / l_[nt];
            f32x4 v;
            v[0] = atn[mt][nt][0] * inv; v[1] = atn[mt][nt][1] * inv;
            v[2] = atn[mt][nt][2] * inv; v[3] = atn[mt][nt][3] * inv;
            stB(bufA0, nt * 16 + l15, M0 + mt * 16 + l4 * 4, pack4v(v));
        }
    __syncthreads();                            // E1

    // ---- ov = attn @ Wo + bo -> sE0 ----
#pragma unroll
    for (int mt = 0; mt < 2; ++mt)
#pragma unroll
        for (int nt = 0; nt < 4; ++nt) acc[mt][nt] = (f32x4){0.f, 0.f, 0.f, 0.f};
    mmG<4>(WoT, 4, M0, 0, bufA0, lane, acc);
#pragma unroll
    for (int mt = 0; mt < 2; ++mt) {
        float4 bb = *(const float4*)(bo + M0 + mt * 16 + l4 * 4);
#pragma unroll
        for (int nt = 0; nt < 4; ++nt) {
            f32x4 v;
            v[0] = acc[mt][nt][0] + bb.x; v[1] = acc[mt][nt][1] + bb.y;
            v[2] = acc[mt][nt][2] + bb.z; v[3] = acc[mt][nt][3] + bb.w;
            stB(sE0, nt * 16 + l15, M0 + mt * 16 + l4 * 4, pack4v(v));
        }
    }
    __syncthreads();                            // E2

    // ---- h1 = lrelu([s_enc | ov] @ W_fc1 + b1) -> bufA0 ----
#pragma unroll
    for (int mt = 0; mt < 2; ++mt)
#pragma unroll
        for (int nt = 0; nt < 4; ++nt) acc[mt][nt] = (f32x4){0.f, 0.f, 0.f, 0.f};
    mmG<4>(W1T, 8, M0, 0, sENC, lane, acc);     // k = 0..127
    mmG<4>(W1T, 8, M0, 4, sE0, lane, acc);      // k = 128..255
#pragma unroll
    for (int mt = 0; mt < 2; ++mt) {
        float4 bb = *(const float4*)(b_fc1 + M0 + mt * 16 + l4 * 4);
#pragma unroll
        for (int nt = 0; nt < 4; ++nt) {
            f32x4 v;
            v[0] = lrelu(acc[mt][nt][0] + bb.x); v[1] = lrelu(acc[mt][nt][1] + bb.y);
            v[2] = lrelu(acc[mt][nt][2] + bb.z); v[3] = lrelu(acc[mt][nt][3] + bb.w);
            stB(bufA0, nt * 16 + l15, M0 + mt * 16 + l4 * 4, pack4v(v));
        }
    }
    __syncthreads();                            // E3: h1 visible; sENC/sE0 reads drained

    // ---- all_q = h1 @ W_fc2 + b2 : wave wid takes K-chunk kc=wid ----
    float* P = (float*)(SMEM + 2 * TRB * LROW); // 32KB overlay on sE0+sE1 (dead)
    {
        bf16x8 a0 = ldA(W2T, 4, 0, wid, lane);
        bf16x8 a1 = ldA(W2T, 4, 16, wid, lane);
#pragma unroll
        for (int nt = 0; nt < 4; ++nt) {
            bf16x8 b = ldB(bufA0, nt * 16, wid, lane);
            f32x4 z = (f32x4){0.f, 0.f, 0.f, 0.f};
            f32x4 c0 = __builtin_amdgcn_mfma_f32_16x16x32_bf16(a0, b, z, 0, 0, 0);
            f32x4 c1 = __builtin_amdgcn_mfma_f32_16x16x32_bf16(a1, b, z, 0, 0, 0);
            *(f32x4*)(P + wid * 2048 + (nt * 16 + l15) * 32 +      l4 * 4) = c0;
            *(f32x4*)(P + wid * 2048 + (nt * 16 + l15) * 32 + 16 + l4 * 4) = c1;
        }
    }
    __syncthreads();                            // E5

    float* S = (float*)(SMEM + TRB * LROW);     // stash [64][33] overlay on bufA1 (dead)
#pragma unroll
    for (int j = 0; j < 8; ++j) {
        int o = t + 256 * j; int row = o >> 5, f = o & 31;
        float v = P[o] + P[2048 + o] + P[4096 + o] + P[6144 + o] + b_fc2[f];
        out_allq[(size_t)(row0 + row) * 32 + f] = v;
        S[row * 33 + f] = v;
    }
    __syncthreads();                            // E6

    // ---- q = all_q[argmax(a[:, :32])] ----
    if (t < TRB) {
        int row = row0 + t;
        float best = -INFINITY; int bi = 0;
#pragma unroll
        for (int jj = 0; jj < 8; ++jj) {
            f32x4 v = ldg_nt4(a + (size_t)row * 256 + jj * 4);
#pragma unroll
            for (int e2 = 0; e2 < 4; ++e2)
                if (v[e2] > best) { best = v[e2]; bi = jj * 4 + e2; }
        }
        out_q[row] = S[t * 33 + bi];
    }
}

extern "C" void kernel_launch(void* const* d_in, const int* in_sizes, int n_in,
                              void* d_out, int out_size, void* d_ws, size_t ws_size,
                              hipStream_t stream)
{
    (void)n_in; (void)out_size; (void)ws_size;
    const float* s        = (const float*)d_in[0];
    const float* a        = (const float*)d_in[1];
    const float* W_enc_s  = (const float*)d_in[2];
    const float* b_enc_s  = (const float*)d_in[3];
    const float* W_enc_sa = (const float*)d_in[4];
    const float* b_enc_sa = (const float*)d_in[5];
    const float* Wq       = (const float*)d_in[6];
    const float* Wk       = (const float*)d_in[7];
    const float* Wv       = (const float*)d_in[8];
    const float* bv       = (const float*)d_in[9];
    const float* Wo       = (const float*)d_in[10];
    const float* bo       = (const float*)d_in[11];
    const float* W_fc1    = (const float*)d_in[12];
    const float* b_fc1    = (const float*)d_in[13];
    const float* W_fc2    = (const float*)d_in[14];
    const float* b_fc2    = (const float*)d_in[15];

    int B = in_sizes[0] / 768;
    float* out_q    = (float*)d_out;
    float* out_allq = out_q + B;
    unsigned short* WS = (unsigned short*)d_ws;

    wprep<<<dim3(896), dim3(256), 0, stream>>>(W_enc_s, W_enc_sa, Wq, Wk, Wv, Wo,
                                               W_fc1, W_fc2, WS);
    ac_mfma<<<dim3(B / TRB), dim3(256), 0, stream>>>(s, a, WS, b_enc_s, b_enc_sa,
                                                     bv, bo, b_fc1, b_fc2,
                                                     out_q, out_allq);
}

// Round 16
// 66.117 us; speedup vs baseline: 4.6426x; 2.1887x over previous
//
#include <hip/hip_runtime.h>
#include <math.h>

// R16 = R11 (best, 65.3us) restored verbatim + T5 s_setprio(1) around the MFMA
// clusters (kv_phase and e-mm). Mechanism: ~1.5-3 co-resident blocks/CU sit at
// DIFFERENT phases, so priority arbitration favors MFMA-issuing waves over
// load-issuing ones (catalog: +4-7% in phase-diverse regime, null in lockstep).
// R15 lesson (3rd confirmation): per-wave state must stay <=~110 regs -> TRB=32, nt=2.

typedef __attribute__((ext_vector_type(8))) short bf16x8;
typedef __attribute__((ext_vector_type(4))) float f32x4;
typedef __attribute__((ext_vector_type(4))) __bf16 bf16x4f;

#define PITCH 136   // bf16 pitch: 272B rows
#define TRB 32

__device__ __forceinline__ float lrelu(float x){ return x > 0.f ? x : 0.01f * x; }

__device__ __forceinline__ unsigned short f2bf(float x){   // wprep only
    union { float f; unsigned u; } c; c.f = x;
    unsigned u = c.u; u += 0x7fffu + ((u >> 16) & 1u);
    return (unsigned short)(u >> 16);
}
__device__ __forceinline__ ushort4 pack4v(f32x4 v){
    union { bf16x4f b; ushort4 u; } c;
    c.b = __builtin_convertvector(v, bf16x4f);   // 2x v_cvt_pk_bf16_f32
    return c.u;
}
__device__ __forceinline__ f32x4 ldg_nt4(const float* p){
    return __builtin_nontemporal_load((const f32x4*)p);
}

// fragment-packed weight load: chunk (m-tile, kc) is 512 bf16 (1KB), lane-major.
__device__ __forceinline__ bf16x8 ldA(const unsigned short* __restrict__ WT, int Kc,
                                      int m0, int kc, int lane){
    return *(const bf16x8*)(WT + ((((size_t)(m0 >> 4)) * Kc + kc) << 9) + lane * 8);
}
__device__ __forceinline__ bf16x8 ldB(const unsigned short* L, int n0, int kc, int lane){
    return *(const bf16x8*)(L + (n0 + (lane & 15)) * PITCH + kc * 32 + (lane >> 4) * 8);
}

template<int NKC>
__device__ __forceinline__ void ldW(const unsigned short* __restrict__ WT, int Kc, int M0,
                                    int kc0, int lane, bf16x8 F[2][NKC]){
#pragma unroll
    for (int mt = 0; mt < 2; ++mt)
#pragma unroll
        for (int kc = 0; kc < NKC; ++kc)
            F[mt][kc] = ldA(WT, Kc, M0 + mt * 16, kc0 + kc, lane);
}

template<int NKC>
__device__ __forceinline__ void mmR(const bf16x8 F[2][NKC], const unsigned short* Ls,
                                    int lane, f32x4 acc[2][2]){
    __builtin_amdgcn_s_setprio(1);
#pragma unroll
    for (int kc = 0; kc < NKC; ++kc) {
        bf16x8 b[2];
#pragma unroll
        for (int nt = 0; nt < 2; ++nt) b[nt] = ldB(Ls, nt * 16, kc, lane);
#pragma unroll
        for (int mt = 0; mt < 2; ++mt)
#pragma unroll
            for (int nt = 0; nt < 2; ++nt)
                acc[mt][nt] = __builtin_amdgcn_mfma_f32_16x16x32_bf16(F[mt][kc], b[nt], acc[mt][nt], 0, 0, 0);
    }
    __builtin_amdgcn_s_setprio(0);
}

template<int NKC>
__device__ __forceinline__ void mmG(const unsigned short* __restrict__ WT, int Kc, int M0,
                                    int kc0, const unsigned short* Ls, int lane,
                                    f32x4 acc[2][2]){
    bf16x8 F[2][NKC];
    ldW<NKC>(WT, Kc, M0, kc0, lane, F);
    mmR<NKC>(F, Ls, lane, acc);
}

// staging loads (non-temporal, f32 in regs); n = -1 => s_i
__device__ __forceinline__ void ld_sa_f(const float* __restrict__ s, const float* __restrict__ a,
                                        int row0, int n, int t, f32x4 sf[3], f32x4& af){
#pragma unroll
    for (int i = 0; i < 3; ++i) {
        int idx = t + 256 * i; int r = idx / 24, c4 = idx % 24;
        sf[i] = ldg_nt4(s + (size_t)(row0 + r) * 768 + 96 + 96 * n + c4 * 4);
    }
    af = ldg_nt4(a + (size_t)(row0 + (t >> 3)) * 256 + 32 + 32 * n + (t & 7) * 4);
}
__device__ __forceinline__ void st_sa(unsigned short* buf, int t,
                                      const f32x4 sf[3], const f32x4 af){
#pragma unroll
    for (int i = 0; i < 3; ++i) {
        int idx = t + 256 * i; int r = idx / 24, c4 = idx % 24;
        *(ushort4*)(buf + r * PITCH + c4 * 4) = pack4v(sf[i]);
    }
    *(ushort4*)(buf + (t >> 3) * PITCH + 96 + (t & 7) * 4) = pack4v(af);
}

// destination offset of element (q=out_row, f=in_col) in fragment-packed layout
__device__ __forceinline__ int froff(int q, int f, int Kc){
    return (((q >> 4) * Kc + (f >> 5)) << 9) + (((f >> 3) & 3) << 7) + ((q & 15) << 3) + (f & 7);
}

// ---- weight prep: fp32 W[in][out] -> bf16 fragment-packed W^T in d_ws ----
__global__ void wprep(const float* __restrict__ Ws, const float* __restrict__ Wsa,
                      const float* __restrict__ Wq_, const float* __restrict__ Wk_,
                      const float* __restrict__ Wv_, const float* __restrict__ Wo_,
                      const float* __restrict__ W1, const float* __restrict__ W2,
                      unsigned short* __restrict__ o)
{
    int id = blockIdx.x * 256 + threadIdx.x;
    if (id >= 229376) return;
    float v; int dst;
    if (id < 12288)        { int q = id / 96, f = id - q * 96;
                             v = Ws[f * 128 + q];              dst = froff(q, f, 3); }
    else if (id < 126976)  { int li = id - 12288; int n = li >> 14; int r = li & 16383;
                             int q = r >> 7, f = r & 127;
                             v = Wsa[n * 16384 + f * 128 + q]; dst = 12288 + n * 16384 + froff(q, f, 4); }
    else if (id < 143360)  { int li = id - 126976; int q = li >> 7, f = li & 127;
                             v = Wq_[f * 128 + q];             dst = 126976 + froff(q, f, 4); }
    else if (id < 159744)  { int li = id - 143360; int q = li >> 7, f = li & 127;
                             v = Wk_[f * 128 + q];             dst = 143360 + froff(q, f, 4); }
    else if (id < 176128)  { int li = id - 159744; int q = li >> 7, f = li & 127;
                             v = Wv_[f * 128 + q];             dst = 159744 + froff(q, f, 4); }
    else if (id < 192512)  { int li = id - 176128; int q = li >> 7, f = li & 127;
                             v = Wo_[f * 128 + q];             dst = 176128 + froff(q, f, 4); }
    else if (id < 225280)  { int li = id - 192512; int q = li >> 8, f = li & 255;
                             v = W1[f * 128 + q];              dst = 192512 + froff(q, f, 8); }
    else                   { int li = id - 225280; int q = li >> 7, f = li & 127;
                             v = W2[f * 32 + q];               dst = 225280 + froff(q, f, 4); }
    o[dst] = f2bf(v);
}

__global__ void __launch_bounds__(256, 2)
ac_mfma(const float* __restrict__ s, const float* __restrict__ a,
        const unsigned short* __restrict__ WS,
        const float* __restrict__ b_enc_s, const float* __restrict__ b_enc_sa,
        const float* __restrict__ bv, const float* __restrict__ bo,
        const float* __restrict__ b_fc1, const float* __restrict__ b_fc2,
        float* __restrict__ out_q, float* __restrict__ out_allq)
{
    // 5 x 8704B buffers = 43,520 B
    __shared__ __align__(16) unsigned short SMEM[5 * TRB * PITCH];
    unsigned short* bufA0 = SMEM;                     // staging even-parity / attn / h1
    unsigned short* bufA1 = SMEM + TRB * PITCH;       // staging odd-parity ; P-overlay
    unsigned short* sE0   = SMEM + 2 * TRB * PITCH;   // e(even) / ov ; P-overlay
    unsigned short* sE1   = SMEM + 3 * TRB * PITCH;   // e(odd)
    unsigned short* sENC  = SMEM + 4 * TRB * PITCH;   // s_enc ; S-overlay

    const int t = threadIdx.x, lane = t & 63, wid = t >> 6;
    const int l15 = lane & 15, l4 = lane >> 4;
    const int M0 = 32 * wid;
    const int row0 = blockIdx.x * TRB;
    const float rsd = 0.17677669529663687f;  // 1/sqrt(32)

    const unsigned short* WencST = WS;
    const unsigned short* WsaT   = WS + 12288;
    const unsigned short* WqT    = WS + 126976;
    const unsigned short* WkT    = WS + 143360;
    const unsigned short* WvT    = WS + 159744;
    const unsigned short* WoT    = WS + 176128;
    const unsigned short* W1T    = WS + 192512;
    const unsigned short* W2T    = WS + 225280;

    f32x4 sf[3]; f32x4 af;

    // ---- prologue: stage s_i -> bufA0 ----
    ld_sa_f(s, a, row0, -1, t, sf, af);
    st_sa(bufA0, t, sf, af);
    __syncthreads();                            // P1

    // ---- s_enc = lrelu(s_i @ Wenc_s + b) ----
    f32x4 acc[2][2];
#pragma unroll
    for (int mt = 0; mt < 2; ++mt)
#pragma unroll
        for (int nt = 0; nt < 2; ++nt) acc[mt][nt] = (f32x4){0.f, 0.f, 0.f, 0.f};
    mmG<3>(WencST, 3, M0, 0, bufA0, lane, acc);
    ld_sa_f(s, a, row0, 0, t, sf, af);          // issue agent-0 staging loads
    __syncthreads();                            // P2: enc reads of bufA0 done
#pragma unroll
    for (int mt = 0; mt < 2; ++mt) {
        float4 bb = *(const float4*)(b_enc_s + M0 + mt * 16 + l4 * 4);
#pragma unroll
        for (int nt = 0; nt < 2; ++nt) {
            f32x4 v;
            v[0] = lrelu(acc[mt][nt][0] + bb.x); v[1] = lrelu(acc[mt][nt][1] + bb.y);
            v[2] = lrelu(acc[mt][nt][2] + bb.z); v[3] = lrelu(acc[mt][nt][3] + bb.w);
            *(ushort4*)(sENC + (nt * 16 + l15) * PITCH + M0 + mt * 16 + l4 * 4) = pack4v(v);
        }
    }
    st_sa(bufA1, t, sf, af);                    // staging(0) -> bufA1
    __syncthreads();                            // P3: sENC + staging(0) visible

    // ---- Q (register-resident; wave wid == head wid) ----
    f32x4 q[2][2];
#pragma unroll
    for (int mt = 0; mt < 2; ++mt)
#pragma unroll
        for (int nt = 0; nt < 2; ++nt) q[mt][nt] = (f32x4){0.f, 0.f, 0.f, 0.f};
    mmG<4>(WqT, 4, M0, 0, sENC, lane, q);

    float4 bvf[2];
#pragma unroll
    for (int mt = 0; mt < 2; ++mt) bvf[mt] = *(const float4*)(bv + M0 + mt * 16 + l4 * 4);

    f32x4 atn[2][2];
#pragma unroll
    for (int mt = 0; mt < 2; ++mt)
#pragma unroll
        for (int nt = 0; nt < 2; ++nt) atn[mt][nt] = (f32x4){0.f, 0.f, 0.f, 0.f};
    float m_[2] = {-INFINITY, -INFINITY}, l_[2] = {0.f, 0.f};

    // merged K+V + online-softmax for one e-tile (single pass over EB)
    auto kv_phase = [&](const unsigned short* EB){
        f32x4 kk[2][2], vv[2][2];
#pragma unroll
        for (int mt = 0; mt < 2; ++mt)
#pragma unroll
            for (int nt = 0; nt < 2; ++nt) {
                kk[mt][nt] = (f32x4){0.f, 0.f, 0.f, 0.f};
                vv[mt][nt] = (f32x4){0.f, 0.f, 0.f, 0.f};
            }
        __builtin_amdgcn_s_setprio(1);
#pragma unroll
        for (int kc = 0; kc < 4; ++kc) {
            bf16x8 b[2];
#pragma unroll
            for (int nt = 0; nt < 2; ++nt) b[nt] = ldB(EB, nt * 16, kc, lane);
#pragma unroll
            for (int mt = 0; mt < 2; ++mt) {
                bf16x8 fk = ldA(WkT, 4, M0 + mt * 16, kc, lane);
                bf16x8 fv = ldA(WvT, 4, M0 + mt * 16, kc, lane);
#pragma unroll
                for (int nt = 0; nt < 2; ++nt) {
                    kk[mt][nt] = __builtin_amdgcn_mfma_f32_16x16x32_bf16(fk, b[nt], kk[mt][nt], 0, 0, 0);
                    vv[mt][nt] = __builtin_amdgcn_mfma_f32_16x16x32_bf16(fv, b[nt], vv[mt][nt], 0, 0, 0);
                }
            }
        }
        __builtin_amdgcn_s_setprio(0);
        float pr[2], corr[2];
#pragma unroll
        for (int nt = 0; nt < 2; ++nt) {
            float p = 0.f;
#pragma unroll
            for (int mt = 0; mt < 2; ++mt)
#pragma unroll
                for (int r = 0; r < 4; ++r) p = fmaf(q[mt][nt][r], kk[mt][nt][r], p);
            p += __shfl_xor(p, 16);
            p += __shfl_xor(p, 32);
            float sc = p * rsd;
            float mo = m_[nt], mn = fmaxf(mo, sc);
            pr[nt]   = __expf(sc - mn);
            corr[nt] = __expf(mo - mn);
            l_[nt] = l_[nt] * corr[nt] + pr[nt];
            m_[nt] = mn;
        }
#pragma unroll
        for (int mt = 0; mt < 2; ++mt)
#pragma unroll
            for (int nt = 0; nt < 2; ++nt)
#pragma unroll
                for (int r = 0; r < 4; ++r) {
                    float vx = lrelu(vv[mt][nt][r] + ((const float*)&bvf[mt])[r]);
                    atn[mt][nt][r] = fmaf(atn[mt][nt][r], corr[nt], pr[nt] * vx);
                }
    };

    // ---- agent loop: ONE barrier per iteration ----
    for (int n = 0; n < 7; ++n) {
        unsigned short* stageRd = (n & 1) ? bufA0 : bufA1;
        unsigned short* stageWr = (n & 1) ? bufA1 : bufA0;
        unsigned short* eWr     = (n & 1) ? sE1 : sE0;
        unsigned short* eRd     = (n & 1) ? sE0 : sE1;

        if (n < 6) ld_sa_f(s, a, row0, n + 1, t, sf, af);   // issue nt loads early
        bf16x8 F[2][4];
        ldW<4>(WsaT + n * 16384, 4, M0, 0, lane, F);        // issue Wsa(n) frags

        if (n) kv_phase(eRd);                               // KV(n-1) under the loads

        f32x4 e[2][2];
#pragma unroll
        for (int mt = 0; mt < 2; ++mt)
#pragma unroll
            for (int nt = 0; nt < 2; ++nt) e[mt][nt] = (f32x4){0.f, 0.f, 0.f, 0.f};
        mmR<4>(F, stageRd, lane, e);

#pragma unroll
        for (int mt = 0; mt < 2; ++mt) {
            float4 bb = *(const float4*)(b_enc_sa + n * 128 + M0 + mt * 16 + l4 * 4);
#pragma unroll
            for (int nt = 0; nt < 2; ++nt) {
                f32x4 v;
                v[0] = lrelu(e[mt][nt][0] + bb.x); v[1] = lrelu(e[mt][nt][1] + bb.y);
                v[2] = lrelu(e[mt][nt][2] + bb.z); v[3] = lrelu(e[mt][nt][3] + bb.w);
                *(ushort4*)(eWr + (nt * 16 + l15) * PITCH + M0 + mt * 16 + l4 * 4) = pack4v(v);
            }
        }
        if (n < 6) st_sa(stageWr, t, sf, af);
        __syncthreads();                        // the one barrier
    }
    kv_phase(sE0);                              // agent 6 (e(6) is in sE0)

    // ---- attn normalize -> bufA0 ----
#pragma unroll
    for (int mt = 0; mt < 2; ++mt)
#pragma unroll
        for (int nt = 0; nt < 2; ++nt) {
            float inv = 1.f / l_[nt];
            f32x4 v;
            v[0] = atn[mt][nt][0] * inv; v[1] = atn[mt][nt][1] * inv;
            v[2] = atn[mt][nt][2] * inv; v[3] = atn[mt][nt][3] * inv;
            *(ushort4*)(bufA0 + (nt * 16 + l15) * PITCH + M0 + mt * 16 + l4 * 4) = pack4v(v);
        }
    __syncthreads();                            // E1

    // ---- ov = attn @ Wo + bo -> sE0 ----
#pragma unroll
    for (int mt = 0; mt < 2; ++mt)
#pragma unroll
        for (int nt = 0; nt < 2; ++nt) acc[mt][nt] = (f32x4){0.f, 0.f, 0.f, 0.f};
    mmG<4>(WoT, 4, M0, 0, bufA0, lane, acc);
#pragma unroll
    for (int mt = 0; mt < 2; ++mt) {
        float4 bb = *(const float4*)(bo + M0 + mt * 16 + l4 * 4);
#pragma unroll
        for (int nt = 0; nt < 2; ++nt) {
            f32x4 v;
            v[0] = acc[mt][nt][0] + bb.x; v[1] = acc[mt][nt][1] + bb.y;
            v[2] = acc[mt][nt][2] + bb.z; v[3] = acc[mt][nt][3] + bb.w;
            *(ushort4*)(sE0 + (nt * 16 + l15) * PITCH + M0 + mt * 16 + l4 * 4) = pack4v(v);
        }
    }
    __syncthreads();                            // E2

    // ---- h1 = lrelu([s_enc | ov] @ W_fc1 + b1) -> bufA0 ----
#pragma unroll
    for (int mt = 0; mt < 2; ++mt)
#pragma unroll
        for (int nt = 0; nt < 2; ++nt) acc[mt][nt] = (f32x4){0.f, 0.f, 0.f, 0.f};
    mmG<4>(W1T, 8, M0, 0, sENC, lane, acc);     // k = 0..127
    mmG<4>(W1T, 8, M0, 4, sE0, lane, acc);      // k = 128..255
#pragma unroll
    for (int mt = 0; mt < 2; ++mt) {
        float4 bb = *(const float4*)(b_fc1 + M0 + mt * 16 + l4 * 4);
#pragma unroll
        for (int nt = 0; nt < 2; ++nt) {
            f32x4 v;
            v[0] = lrelu(acc[mt][nt][0] + bb.x); v[1] = lrelu(acc[mt][nt][1] + bb.y);
            v[2] = lrelu(acc[mt][nt][2] + bb.z); v[3] = lrelu(acc[mt][nt][3] + bb.w);
            *(ushort4*)(bufA0 + (nt * 16 + l15) * PITCH + M0 + mt * 16 + l4 * 4) = pack4v(v);
        }
    }
    __syncthreads();                            // E4: h1 visible; fc1 LDS reads drained

    // ---- all_q = h1 @ W_fc2 + b2 : wave wid takes K-chunk kc=wid ----
    float* P = (float*)(SMEM + TRB * PITCH);    // 16KB overlay on bufA1+sE0 (dead)
    {
        bf16x8 a0 = ldA(W2T, 4, 0, wid, lane);
        bf16x8 a1 = ldA(W2T, 4, 16, wid, lane);
        bf16x8 b0 = ldB(bufA0, 0, wid, lane);
        bf16x8 b1 = ldB(bufA0, 16, wid, lane);
        f32x4 z = (f32x4){0.f, 0.f, 0.f, 0.f};
        f32x4 c00 = __builtin_amdgcn_mfma_f32_16x16x32_bf16(a0, b0, z, 0, 0, 0);
        f32x4 c01 = __builtin_amdgcn_mfma_f32_16x16x32_bf16(a0, b1, z, 0, 0, 0);
        f32x4 c10 = __builtin_amdgcn_mfma_f32_16x16x32_bf16(a1, b0, z, 0, 0, 0);
        f32x4 c11 = __builtin_amdgcn_mfma_f32_16x16x32_bf16(a1, b1, z, 0, 0, 0);
        *(f32x4*)(P + wid * 1024 + (l15     ) * 32 +      l4 * 4) = c00;
        *(f32x4*)(P + wid * 1024 + (16 + l15) * 32 +      l4 * 4) = c01;
        *(f32x4*)(P + wid * 1024 + (l15     ) * 32 + 16 + l4 * 4) = c10;
        *(f32x4*)(P + wid * 1024 + (16 + l15) * 32 + 16 + l4 * 4) = c11;
    }
    __syncthreads();                            // E5

    float* S = (float*)sENC;                    // stash [32][33] overlay (sENC dead)
#pragma unroll
    for (int j = 0; j < 4; ++j) {
        int o = t + 256 * j; int row = o >> 5, f = o & 31;
        float v = P[row * 32 + f] + P[1024 + row * 32 + f]
                + P[2048 + row * 32 + f] + P[3072 + row * 32 + f] + b_fc2[f];
        out_allq[(size_t)(row0 + row) * 32 + f] = v;
        S[row * 33 + f] = v;
    }
    __syncthreads();                            // E6

    // ---- q = all_q[argmax(a[:, :32])] ----
    if (t < TRB) {
        int row = row0 + t;
        float best = -INFINITY; int bi = 0;
#pragma unroll
        for (int jj = 0; jj < 8; ++jj) {
            f32x4 v = ldg_nt4(a + (size_t)row * 256 + jj * 4);
#pragma unroll
            for (int e2 = 0; e2 < 4; ++e2)
                if (v[e2] > best) { best = v[e2]; bi = jj * 4 + e2; }
        }
        out_q[row] = S[t * 33 + bi];
    }
}

extern "C" void kernel_launch(void* const* d_in, const int* in_sizes, int n_in,
                              void* d_out, int out_size, void* d_ws, size_t ws_size,
                              hipStream_t stream)
{
    (void)n_in; (void)out_size; (void)ws_size;
    const float* s        = (const float*)d_in[0];
    const float* a        = (const float*)d_in[1];
    const float* W_enc_s  = (const float*)d_in[2];
    const float* b_enc_s  = (const float*)d_in[3];
    const float* W_enc_sa = (const float*)d_in[4];
    const float* b_enc_sa = (const float*)d_in[5];
    const float* Wq       = (const float*)d_in[6];
    const float* Wk       = (const float*)d_in[7];
    const float* Wv       = (const float*)d_in[8];
    const float* bv       = (const float*)d_in[9];
    const float* Wo       = (const float*)d_in[10];
    const float* bo       = (const float*)d_in[11];
    const float* W_fc1    = (const float*)d_in[12];
    const float* b_fc1    = (const float*)d_in[13];
    const float* W_fc2    = (const float*)d_in[14];
    const float* b_fc2    = (const float*)d_in[15];

    int B = in_sizes[0] / 768;
    float* out_q    = (float*)d_out;
    float* out_allq = out_q + B;
    unsigned short* WS = (unsigned short*)d_ws;

    wprep<<<dim3(896), dim3(256), 0, stream>>>(W_enc_s, W_enc_sa, Wq, Wk, Wv, Wo,
                                               W_fc1, W_fc2, WS);
    ac_mfma<<<dim3(B / TRB), dim3(256), 0, stream>>>(s, a, WS, b_enc_s, b_enc_sa,
                                                     bv, bo, b_fc1, b_fc2,
                                                     out_q, out_allq);
}

// Round 17
// 63.851 us; speedup vs baseline: 4.8073x; 1.0355x over previous
//
#include <hip/hip_runtime.h>
#include <math.h>

// R17 = R16 + Wk/Wv fragments hoisted into registers for the whole agent loop
// (WkF/WvF, 64 regs). L1 (32KB) is evicted by the 32KB/iter Wsa stream, so each
// of the 7 kv_phases was re-pulling 16 fragments from L2 (~200-400cy wall).
// Register arithmetic: peak ~185 < 256 budget at (256,2). R4's version of this
// failed only because it was bundled with TRB=64/nt=4 at a 128-reg budget.
// Tripwire: WRITE_SIZE > 10MB = spill -> revert.

typedef __attribute__((ext_vector_type(8))) short bf16x8;
typedef __attribute__((ext_vector_type(4))) float f32x4;
typedef __attribute__((ext_vector_type(4))) __bf16 bf16x4f;

#define PITCH 136   // bf16 pitch: 272B rows
#define TRB 32

__device__ __forceinline__ float lrelu(float x){ return x > 0.f ? x : 0.01f * x; }

__device__ __forceinline__ unsigned short f2bf(float x){   // wprep only
    union { float f; unsigned u; } c; c.f = x;
    unsigned u = c.u; u += 0x7fffu + ((u >> 16) & 1u);
    return (unsigned short)(u >> 16);
}
__device__ __forceinline__ ushort4 pack4v(f32x4 v){
    union { bf16x4f b; ushort4 u; } c;
    c.b = __builtin_convertvector(v, bf16x4f);   // 2x v_cvt_pk_bf16_f32
    return c.u;
}
__device__ __forceinline__ f32x4 ldg_nt4(const float* p){
    return __builtin_nontemporal_load((const f32x4*)p);
}

// fragment-packed weight load: chunk (m-tile, kc) is 512 bf16 (1KB), lane-major.
__device__ __forceinline__ bf16x8 ldA(const unsigned short* __restrict__ WT, int Kc,
                                      int m0, int kc, int lane){
    return *(const bf16x8*)(WT + ((((size_t)(m0 >> 4)) * Kc + kc) << 9) + lane * 8);
}
__device__ __forceinline__ bf16x8 ldB(const unsigned short* L, int n0, int kc, int lane){
    return *(const bf16x8*)(L + (n0 + (lane & 15)) * PITCH + kc * 32 + (lane >> 4) * 8);
}

template<int NKC>
__device__ __forceinline__ void ldW(const unsigned short* __restrict__ WT, int Kc, int M0,
                                    int kc0, int lane, bf16x8 F[2][NKC]){
#pragma unroll
    for (int mt = 0; mt < 2; ++mt)
#pragma unroll
        for (int kc = 0; kc < NKC; ++kc)
            F[mt][kc] = ldA(WT, Kc, M0 + mt * 16, kc0 + kc, lane);
}

template<int NKC>
__device__ __forceinline__ void mmR(const bf16x8 F[2][NKC], const unsigned short* Ls,
                                    int lane, f32x4 acc[2][2]){
    __builtin_amdgcn_s_setprio(1);
#pragma unroll
    for (int kc = 0; kc < NKC; ++kc) {
        bf16x8 b[2];
#pragma unroll
        for (int nt = 0; nt < 2; ++nt) b[nt] = ldB(Ls, nt * 16, kc, lane);
#pragma unroll
        for (int mt = 0; mt < 2; ++mt)
#pragma unroll
            for (int nt = 0; nt < 2; ++nt)
                acc[mt][nt] = __builtin_amdgcn_mfma_f32_16x16x32_bf16(F[mt][kc], b[nt], acc[mt][nt], 0, 0, 0);
    }
    __builtin_amdgcn_s_setprio(0);
}

template<int NKC>
__device__ __forceinline__ void mmG(const unsigned short* __restrict__ WT, int Kc, int M0,
                                    int kc0, const unsigned short* Ls, int lane,
                                    f32x4 acc[2][2]){
    bf16x8 F[2][NKC];
    ldW<NKC>(WT, Kc, M0, kc0, lane, F);
    mmR<NKC>(F, Ls, lane, acc);
}

// staging loads (non-temporal, f32 in regs); n = -1 => s_i
__device__ __forceinline__ void ld_sa_f(const float* __restrict__ s, const float* __restrict__ a,
                                        int row0, int n, int t, f32x4 sf[3], f32x4& af){
#pragma unroll
    for (int i = 0; i < 3; ++i) {
        int idx = t + 256 * i; int r = idx / 24, c4 = idx % 24;
        sf[i] = ldg_nt4(s + (size_t)(row0 + r) * 768 + 96 + 96 * n + c4 * 4);
    }
    af = ldg_nt4(a + (size_t)(row0 + (t >> 3)) * 256 + 32 + 32 * n + (t & 7) * 4);
}
__device__ __forceinline__ void st_sa(unsigned short* buf, int t,
                                      const f32x4 sf[3], const f32x4 af){
#pragma unroll
    for (int i = 0; i < 3; ++i) {
        int idx = t + 256 * i; int r = idx / 24, c4 = idx % 24;
        *(ushort4*)(buf + r * PITCH + c4 * 4) = pack4v(sf[i]);
    }
    *(ushort4*)(buf + (t >> 3) * PITCH + 96 + (t & 7) * 4) = pack4v(af);
}

// destination offset of element (q=out_row, f=in_col) in fragment-packed layout
__device__ __forceinline__ int froff(int q, int f, int Kc){
    return (((q >> 4) * Kc + (f >> 5)) << 9) + (((f >> 3) & 3) << 7) + ((q & 15) << 3) + (f & 7);
}

// ---- weight prep: fp32 W[in][out] -> bf16 fragment-packed W^T in d_ws ----
__global__ void wprep(const float* __restrict__ Ws, const float* __restrict__ Wsa,
                      const float* __restrict__ Wq_, const float* __restrict__ Wk_,
                      const float* __restrict__ Wv_, const float* __restrict__ Wo_,
                      const float* __restrict__ W1, const float* __restrict__ W2,
                      unsigned short* __restrict__ o)
{
    int id = blockIdx.x * 256 + threadIdx.x;
    if (id >= 229376) return;
    float v; int dst;
    if (id < 12288)        { int q = id / 96, f = id - q * 96;
                             v = Ws[f * 128 + q];              dst = froff(q, f, 3); }
    else if (id < 126976)  { int li = id - 12288; int n = li >> 14; int r = li & 16383;
                             int q = r >> 7, f = r & 127;
                             v = Wsa[n * 16384 + f * 128 + q]; dst = 12288 + n * 16384 + froff(q, f, 4); }
    else if (id < 143360)  { int li = id - 126976; int q = li >> 7, f = li & 127;
                             v = Wq_[f * 128 + q];             dst = 126976 + froff(q, f, 4); }
    else if (id < 159744)  { int li = id - 143360; int q = li >> 7, f = li & 127;
                             v = Wk_[f * 128 + q];             dst = 143360 + froff(q, f, 4); }
    else if (id < 176128)  { int li = id - 159744; int q = li >> 7, f = li & 127;
                             v = Wv_[f * 128 + q];             dst = 159744 + froff(q, f, 4); }
    else if (id < 192512)  { int li = id - 176128; int q = li >> 7, f = li & 127;
                             v = Wo_[f * 128 + q];             dst = 176128 + froff(q, f, 4); }
    else if (id < 225280)  { int li = id - 192512; int q = li >> 8, f = li & 255;
                             v = W1[f * 128 + q];              dst = 192512 + froff(q, f, 8); }
    else                   { int li = id - 225280; int q = li >> 7, f = li & 127;
                             v = W2[f * 32 + q];               dst = 225280 + froff(q, f, 4); }
    o[dst] = f2bf(v);
}

__global__ void __launch_bounds__(256, 2)
ac_mfma(const float* __restrict__ s, const float* __restrict__ a,
        const unsigned short* __restrict__ WS,
        const float* __restrict__ b_enc_s, const float* __restrict__ b_enc_sa,
        const float* __restrict__ bv, const float* __restrict__ bo,
        const float* __restrict__ b_fc1, const float* __restrict__ b_fc2,
        float* __restrict__ out_q, float* __restrict__ out_allq)
{
    // 5 x 8704B buffers = 43,520 B
    __shared__ __align__(16) unsigned short SMEM[5 * TRB * PITCH];
    unsigned short* bufA0 = SMEM;                     // staging even-parity / attn / h1
    unsigned short* bufA1 = SMEM + TRB * PITCH;       // staging odd-parity ; P-overlay
    unsigned short* sE0   = SMEM + 2 * TRB * PITCH;   // e(even) / ov ; P-overlay
    unsigned short* sE1   = SMEM + 3 * TRB * PITCH;   // e(odd)
    unsigned short* sENC  = SMEM + 4 * TRB * PITCH;   // s_enc ; S-overlay

    const int t = threadIdx.x, lane = t & 63, wid = t >> 6;
    const int l15 = lane & 15, l4 = lane >> 4;
    const int M0 = 32 * wid;
    const int row0 = blockIdx.x * TRB;
    const float rsd = 0.17677669529663687f;  // 1/sqrt(32)

    const unsigned short* WencST = WS;
    const unsigned short* WsaT   = WS + 12288;
    const unsigned short* WqT    = WS + 126976;
    const unsigned short* WkT    = WS + 143360;
    const unsigned short* WvT    = WS + 159744;
    const unsigned short* WoT    = WS + 176128;
    const unsigned short* W1T    = WS + 192512;
    const unsigned short* W2T    = WS + 225280;

    f32x4 sf[3]; f32x4 af;

    // ---- prologue: stage s_i -> bufA0 ----
    ld_sa_f(s, a, row0, -1, t, sf, af);
    st_sa(bufA0, t, sf, af);
    __syncthreads();                            // P1

    // ---- s_enc = lrelu(s_i @ Wenc_s + b) ----
    f32x4 acc[2][2];
#pragma unroll
    for (int mt = 0; mt < 2; ++mt)
#pragma unroll
        for (int nt = 0; nt < 2; ++nt) acc[mt][nt] = (f32x4){0.f, 0.f, 0.f, 0.f};
    mmG<3>(WencST, 3, M0, 0, bufA0, lane, acc);
    ld_sa_f(s, a, row0, 0, t, sf, af);          // issue agent-0 staging loads
    __syncthreads();                            // P2: enc reads of bufA0 done
#pragma unroll
    for (int mt = 0; mt < 2; ++mt) {
        float4 bb = *(const float4*)(b_enc_s + M0 + mt * 16 + l4 * 4);
#pragma unroll
        for (int nt = 0; nt < 2; ++nt) {
            f32x4 v;
            v[0] = lrelu(acc[mt][nt][0] + bb.x); v[1] = lrelu(acc[mt][nt][1] + bb.y);
            v[2] = lrelu(acc[mt][nt][2] + bb.z); v[3] = lrelu(acc[mt][nt][3] + bb.w);
            *(ushort4*)(sENC + (nt * 16 + l15) * PITCH + M0 + mt * 16 + l4 * 4) = pack4v(v);
        }
    }
    st_sa(bufA1, t, sf, af);                    // staging(0) -> bufA1
    __syncthreads();                            // P3: sENC + staging(0) visible

    // ---- Q (register-resident; wave wid == head wid) ----
    f32x4 q[2][2];
#pragma unroll
    for (int mt = 0; mt < 2; ++mt)
#pragma unroll
        for (int nt = 0; nt < 2; ++nt) q[mt][nt] = (f32x4){0.f, 0.f, 0.f, 0.f};
    mmG<4>(WqT, 4, M0, 0, sENC, lane, q);

    // ---- hoist Wk/Wv fragments for the whole agent loop (64 regs) ----
    bf16x8 WkF[2][4], WvF[2][4];
    ldW<4>(WkT, 4, M0, 0, lane, WkF);
    ldW<4>(WvT, 4, M0, 0, lane, WvF);

    float4 bvf[2];
#pragma unroll
    for (int mt = 0; mt < 2; ++mt) bvf[mt] = *(const float4*)(bv + M0 + mt * 16 + l4 * 4);

    f32x4 atn[2][2];
#pragma unroll
    for (int mt = 0; mt < 2; ++mt)
#pragma unroll
        for (int nt = 0; nt < 2; ++nt) atn[mt][nt] = (f32x4){0.f, 0.f, 0.f, 0.f};
    float m_[2] = {-INFINITY, -INFINITY}, l_[2] = {0.f, 0.f};

    // merged K+V + online-softmax for one e-tile (frags in regs; single LDS pass)
    auto kv_phase = [&](const unsigned short* EB){
        f32x4 kk[2][2], vv[2][2];
#pragma unroll
        for (int mt = 0; mt < 2; ++mt)
#pragma unroll
            for (int nt = 0; nt < 2; ++nt) {
                kk[mt][nt] = (f32x4){0.f, 0.f, 0.f, 0.f};
                vv[mt][nt] = (f32x4){0.f, 0.f, 0.f, 0.f};
            }
        __builtin_amdgcn_s_setprio(1);
#pragma unroll
        for (int kc = 0; kc < 4; ++kc) {
            bf16x8 b[2];
#pragma unroll
            for (int nt = 0; nt < 2; ++nt) b[nt] = ldB(EB, nt * 16, kc, lane);
#pragma unroll
            for (int mt = 0; mt < 2; ++mt)
#pragma unroll
                for (int nt = 0; nt < 2; ++nt) {
                    kk[mt][nt] = __builtin_amdgcn_mfma_f32_16x16x32_bf16(WkF[mt][kc], b[nt], kk[mt][nt], 0, 0, 0);
                    vv[mt][nt] = __builtin_amdgcn_mfma_f32_16x16x32_bf16(WvF[mt][kc], b[nt], vv[mt][nt], 0, 0, 0);
                }
        }
        __builtin_amdgcn_s_setprio(0);
        float pr[2], corr[2];
#pragma unroll
        for (int nt = 0; nt < 2; ++nt) {
            float p = 0.f;
#pragma unroll
            for (int mt = 0; mt < 2; ++mt)
#pragma unroll
                for (int r = 0; r < 4; ++r) p = fmaf(q[mt][nt][r], kk[mt][nt][r], p);
            p += __shfl_xor(p, 16);
            p += __shfl_xor(p, 32);
            float sc = p * rsd;
            float mo = m_[nt], mn = fmaxf(mo, sc);
            pr[nt]   = __expf(sc - mn);
            corr[nt] = __expf(mo - mn);
            l_[nt] = l_[nt] * corr[nt] + pr[nt];
            m_[nt] = mn;
        }
#pragma unroll
        for (int mt = 0; mt < 2; ++mt)
#pragma unroll
            for (int nt = 0; nt < 2; ++nt)
#pragma unroll
                for (int r = 0; r < 4; ++r) {
                    float vx = lrelu(vv[mt][nt][r] + ((const float*)&bvf[mt])[r]);
                    atn[mt][nt][r] = fmaf(atn[mt][nt][r], corr[nt], pr[nt] * vx);
                }
    };

    // ---- agent loop: ONE barrier per iteration ----
    for (int n = 0; n < 7; ++n) {
        unsigned short* stageRd = (n & 1) ? bufA0 : bufA1;
        unsigned short* stageWr = (n & 1) ? bufA1 : bufA0;
        unsigned short* eWr     = (n & 1) ? sE1 : sE0;
        unsigned short* eRd     = (n & 1) ? sE0 : sE1;

        if (n < 6) ld_sa_f(s, a, row0, n + 1, t, sf, af);   // issue nt loads early
        bf16x8 F[2][4];
        ldW<4>(WsaT + n * 16384, 4, M0, 0, lane, F);        // issue Wsa(n) frags

        if (n) kv_phase(eRd);                               // KV(n-1) under the loads

        f32x4 e[2][2];
#pragma unroll
        for (int mt = 0; mt < 2; ++mt)
#pragma unroll
            for (int nt = 0; nt < 2; ++nt) e[mt][nt] = (f32x4){0.f, 0.f, 0.f, 0.f};
        mmR<4>(F, stageRd, lane, e);

#pragma unroll
        for (int mt = 0; mt < 2; ++mt) {
            float4 bb = *(const float4*)(b_enc_sa + n * 128 + M0 + mt * 16 + l4 * 4);
#pragma unroll
            for (int nt = 0; nt < 2; ++nt) {
                f32x4 v;
                v[0] = lrelu(e[mt][nt][0] + bb.x); v[1] = lrelu(e[mt][nt][1] + bb.y);
                v[2] = lrelu(e[mt][nt][2] + bb.z); v[3] = lrelu(e[mt][nt][3] + bb.w);
                *(ushort4*)(eWr + (nt * 16 + l15) * PITCH + M0 + mt * 16 + l4 * 4) = pack4v(v);
            }
        }
        if (n < 6) st_sa(stageWr, t, sf, af);
        __syncthreads();                        // the one barrier
    }
    kv_phase(sE0);                              // agent 6 (e(6) is in sE0)

    // ---- attn normalize -> bufA0 ----
#pragma unroll
    for (int mt = 0; mt < 2; ++mt)
#pragma unroll
        for (int nt = 0; nt < 2; ++nt) {
            float inv = 1.f / l_[nt];
            f32x4 v;
            v[0] = atn[mt][nt][0] * inv; v[1] = atn[mt][nt][1] * inv;
            v[2] = atn[mt][nt][2] * inv; v[3] = atn[mt][nt][3] * inv;
            *(ushort4*)(bufA0 + (nt * 16 + l15) * PITCH + M0 + mt * 16 + l4 * 4) = pack4v(v);
        }
    __syncthreads();                            // E1

    // ---- ov = attn @ Wo + bo -> sE0 ----
#pragma unroll
    for (int mt = 0; mt < 2; ++mt)
#pragma unroll
        for (int nt = 0; nt < 2; ++nt) acc[mt][nt] = (f32x4){0.f, 0.f, 0.f, 0.f};
    mmG<4>(WoT, 4, M0, 0, bufA0, lane, acc);
#pragma unroll
    for (int mt = 0; mt < 2; ++mt) {
        float4 bb = *(const float4*)(bo + M0 + mt * 16 + l4 * 4);
#pragma unroll
        for (int nt = 0; nt < 2; ++nt) {
            f32x4 v;
            v[0] = acc[mt][nt][0] + bb.x; v[1] = acc[mt][nt][1] + bb.y;
            v[2] = acc[mt][nt][2] + bb.z; v[3] = acc[mt][nt][3] + bb.w;
            *(ushort4*)(sE0 + (nt * 16 + l15) * PITCH + M0 + mt * 16 + l4 * 4) = pack4v(v);
        }
    }
    __syncthreads();                            // E2

    // ---- h1 = lrelu([s_enc | ov] @ W_fc1 + b1) -> bufA0 ----
#pragma unroll
    for (int mt = 0; mt < 2; ++mt)
#pragma unroll
        for (int nt = 0; nt < 2; ++nt) acc[mt][nt] = (f32x4){0.f, 0.f, 0.f, 0.f};
    mmG<4>(W1T, 8, M0, 0, sENC, lane, acc);     // k = 0..127
    mmG<4>(W1T, 8, M0, 4, sE0, lane, acc);      // k = 128..255
#pragma unroll
    for (int mt = 0; mt < 2; ++mt) {
        float4 bb = *(const float4*)(b_fc1 + M0 + mt * 16 + l4 * 4);
#pragma unroll
        for (int nt = 0; nt < 2; ++nt) {
            f32x4 v;
            v[0] = lrelu(acc[mt][nt][0] + bb.x); v[1] = lrelu(acc[mt][nt][1] + bb.y);
            v[2] = lrelu(acc[mt][nt][2] + bb.z); v[3] = lrelu(acc[mt][nt][3] + bb.w);
            *(ushort4*)(bufA0 + (nt * 16 + l15) * PITCH + M0 + mt * 16 + l4 * 4) = pack4v(v);
        }
    }
    __syncthreads();                            // E4: h1 visible; fc1 LDS reads drained

    // ---- all_q = h1 @ W_fc2 + b2 : wave wid takes K-chunk kc=wid ----
    float* P = (float*)(SMEM + TRB * PITCH);    // 16KB overlay on bufA1+sE0 (dead)
    {
        bf16x8 a0 = ldA(W2T, 4, 0, wid, lane);
        bf16x8 a1 = ldA(W2T, 4, 16, wid, lane);
        bf16x8 b0 = ldB(bufA0, 0, wid, lane);
        bf16x8 b1 = ldB(bufA0, 16, wid, lane);
        f32x4 z = (f32x4){0.f, 0.f, 0.f, 0.f};
        f32x4 c00 = __builtin_amdgcn_mfma_f32_16x16x32_bf16(a0, b0, z, 0, 0, 0);
        f32x4 c01 = __builtin_amdgcn_mfma_f32_16x16x32_bf16(a0, b1, z, 0, 0, 0);
        f32x4 c10 = __builtin_amdgcn_mfma_f32_16x16x32_bf16(a1, b0, z, 0, 0, 0);
        f32x4 c11 = __builtin_amdgcn_mfma_f32_16x16x32_bf16(a1, b1, z, 0, 0, 0);
        *(f32x4*)(P + wid * 1024 + (l15     ) * 32 +      l4 * 4) = c00;
        *(f32x4*)(P + wid * 1024 + (16 + l15) * 32 +      l4 * 4) = c01;
        *(f32x4*)(P + wid * 1024 + (l15     ) * 32 + 16 + l4 * 4) = c10;
        *(f32x4*)(P + wid * 1024 + (16 + l15) * 32 + 16 + l4 * 4) = c11;
    }
    __syncthreads();                            // E5

    float* S = (float*)sENC;                    // stash [32][33] overlay (sENC dead)
#pragma unroll
    for (int j = 0; j < 4; ++j) {
        int o = t + 256 * j; int row = o >> 5, f = o & 31;
        float v = P[row * 32 + f] + P[1024 + row * 32 + f]
                + P[2048 + row * 32 + f] + P[3072 + row * 32 + f] + b_fc2[f];
        out_allq[(size_t)(row0 + row) * 32 + f] = v;
        S[row * 33 + f] = v;
    }
    __syncthreads();                            // E6

    // ---- q = all_q[argmax(a[:, :32])] ----
    if (t < TRB) {
        int row = row0 + t;
        float best = -INFINITY; int bi = 0;
#pragma unroll
        for (int jj = 0; jj < 8; ++jj) {
            f32x4 v = ldg_nt4(a + (size_t)row * 256 + jj * 4);
#pragma unroll
            for (int e2 = 0; e2 < 4; ++e2)
                if (v[e2] > best) { best = v[e2]; bi = jj * 4 + e2; }
        }
        out_q[row] = S[t * 33 + bi];
    }
}

extern "C" void kernel_launch(void* const* d_in, const int* in_sizes, int n_in,
                              void* d_out, int out_size, void* d_ws, size_t ws_size,
                              hipStream_t stream)
{
    (void)n_in; (void)out_size; (void)ws_size;
    const float* s        = (const float*)d_in[0];
    const float* a        = (const float*)d_in[1];
    const float* W_enc_s  = (const float*)d_in[2];
    const float* b_enc_s  = (const float*)d_in[3];
    const float* W_enc_sa = (const float*)d_in[4];
    const float* b_enc_sa = (const float*)d_in[5];
    const float* Wq       = (const float*)d_in[6];
    const float* Wk       = (const float*)d_in[7];
    const float* Wv       = (const float*)d_in[8];
    const float* bv       = (const float*)d_in[9];
    const float* Wo       = (const float*)d_in[10];
    const float* bo       = (const float*)d_in[11];
    const float* W_fc1    = (const float*)d_in[12];
    const float* b_fc1    = (const float*)d_in[13];
    const float* W_fc2    = (const float*)d_in[14];
    const float* b_fc2    = (const float*)d_in[15];

    int B = in_sizes[0] / 768;
    float* out_q    = (float*)d_out;
    float* out_allq = out_q + B;
    unsigned short* WS = (unsigned short*)d_ws;

    wprep<<<dim3(896), dim3(256), 0, stream>>>(W_enc_s, W_enc_sa, Wq, Wk, Wv, Wo,
                                               W_fc1, W_fc2, WS);
    ac_mfma<<<dim3(B / TRB), dim3(256), 0, stream>>>(s, a, WS, b_enc_s, b_enc_sa,
                                                     bv, bo, b_fc1, b_fc2,
                                                     out_q, out_allq);
}

// Round 18
// 62.958 us; speedup vs baseline: 4.8756x; 1.0142x over previous
//
#include <hip/hip_runtime.h>
#include <math.h>

// R18 = R17 + epilogue software-pipelining:
//  (a) h1 first half (sENC @ W1[0:128]) computed BEFORE E1 (sENC stable since P3)
//      -> overlaps attn-normalize + barrier instead of serializing after E2,
//  (b) Wo fragments prefetched before the normalize (used after E1),
//      W1-half2 fragments prefetched after E1 (used after E2),
//      W2 fragments prefetched before E4 (used after E4).
// Deletes ~2 serial phases (~4-5k cy) from the 14k-cycle epilogue chain.
// Extra live state ~48 regs across 1-2 barriers; peak ~170 < 256 budget.

typedef __attribute__((ext_vector_type(8))) short bf16x8;
typedef __attribute__((ext_vector_type(4))) float f32x4;
typedef __attribute__((ext_vector_type(4))) __bf16 bf16x4f;

#define PITCH 136   // bf16 pitch: 272B rows
#define TRB 32

__device__ __forceinline__ float lrelu(float x){ return x > 0.f ? x : 0.01f * x; }

__device__ __forceinline__ unsigned short f2bf(float x){   // wprep only
    union { float f; unsigned u; } c; c.f = x;
    unsigned u = c.u; u += 0x7fffu + ((u >> 16) & 1u);
    return (unsigned short)(u >> 16);
}
__device__ __forceinline__ ushort4 pack4v(f32x4 v){
    union { bf16x4f b; ushort4 u; } c;
    c.b = __builtin_convertvector(v, bf16x4f);   // 2x v_cvt_pk_bf16_f32
    return c.u;
}
__device__ __forceinline__ f32x4 ldg_nt4(const float* p){
    return __builtin_nontemporal_load((const f32x4*)p);
}

// fragment-packed weight load: chunk (m-tile, kc) is 512 bf16 (1KB), lane-major.
__device__ __forceinline__ bf16x8 ldA(const unsigned short* __restrict__ WT, int Kc,
                                      int m0, int kc, int lane){
    return *(const bf16x8*)(WT + ((((size_t)(m0 >> 4)) * Kc + kc) << 9) + lane * 8);
}
__device__ __forceinline__ bf16x8 ldB(const unsigned short* L, int n0, int kc, int lane){
    return *(const bf16x8*)(L + (n0 + (lane & 15)) * PITCH + kc * 32 + (lane >> 4) * 8);
}

template<int NKC>
__device__ __forceinline__ void ldW(const unsigned short* __restrict__ WT, int Kc, int M0,
                                    int kc0, int lane, bf16x8 F[2][NKC]){
#pragma unroll
    for (int mt = 0; mt < 2; ++mt)
#pragma unroll
        for (int kc = 0; kc < NKC; ++kc)
            F[mt][kc] = ldA(WT, Kc, M0 + mt * 16, kc0 + kc, lane);
}

template<int NKC>
__device__ __forceinline__ void mmR(const bf16x8 F[2][NKC], const unsigned short* Ls,
                                    int lane, f32x4 acc[2][2]){
    __builtin_amdgcn_s_setprio(1);
#pragma unroll
    for (int kc = 0; kc < NKC; ++kc) {
        bf16x8 b[2];
#pragma unroll
        for (int nt = 0; nt < 2; ++nt) b[nt] = ldB(Ls, nt * 16, kc, lane);
#pragma unroll
        for (int mt = 0; mt < 2; ++mt)
#pragma unroll
            for (int nt = 0; nt < 2; ++nt)
                acc[mt][nt] = __builtin_amdgcn_mfma_f32_16x16x32_bf16(F[mt][kc], b[nt], acc[mt][nt], 0, 0, 0);
    }
    __builtin_amdgcn_s_setprio(0);
}

template<int NKC>
__device__ __forceinline__ void mmG(const unsigned short* __restrict__ WT, int Kc, int M0,
                                    int kc0, const unsigned short* Ls, int lane,
                                    f32x4 acc[2][2]){
    bf16x8 F[2][NKC];
    ldW<NKC>(WT, Kc, M0, kc0, lane, F);
    mmR<NKC>(F, Ls, lane, acc);
}

// staging loads (non-temporal, f32 in regs); n = -1 => s_i
__device__ __forceinline__ void ld_sa_f(const float* __restrict__ s, const float* __restrict__ a,
                                        int row0, int n, int t, f32x4 sf[3], f32x4& af){
#pragma unroll
    for (int i = 0; i < 3; ++i) {
        int idx = t + 256 * i; int r = idx / 24, c4 = idx % 24;
        sf[i] = ldg_nt4(s + (size_t)(row0 + r) * 768 + 96 + 96 * n + c4 * 4);
    }
    af = ldg_nt4(a + (size_t)(row0 + (t >> 3)) * 256 + 32 + 32 * n + (t & 7) * 4);
}
__device__ __forceinline__ void st_sa(unsigned short* buf, int t,
                                      const f32x4 sf[3], const f32x4 af){
#pragma unroll
    for (int i = 0; i < 3; ++i) {
        int idx = t + 256 * i; int r = idx / 24, c4 = idx % 24;
        *(ushort4*)(buf + r * PITCH + c4 * 4) = pack4v(sf[i]);
    }
    *(ushort4*)(buf + (t >> 3) * PITCH + 96 + (t & 7) * 4) = pack4v(af);
}

// destination offset of element (q=out_row, f=in_col) in fragment-packed layout
__device__ __forceinline__ int froff(int q, int f, int Kc){
    return (((q >> 4) * Kc + (f >> 5)) << 9) + (((f >> 3) & 3) << 7) + ((q & 15) << 3) + (f & 7);
}

// ---- weight prep: fp32 W[in][out] -> bf16 fragment-packed W^T in d_ws ----
__global__ void wprep(const float* __restrict__ Ws, const float* __restrict__ Wsa,
                      const float* __restrict__ Wq_, const float* __restrict__ Wk_,
                      const float* __restrict__ Wv_, const float* __restrict__ Wo_,
                      const float* __restrict__ W1, const float* __restrict__ W2,
                      unsigned short* __restrict__ o)
{
    int id = blockIdx.x * 256 + threadIdx.x;
    if (id >= 229376) return;
    float v; int dst;
    if (id < 12288)        { int q = id / 96, f = id - q * 96;
                             v = Ws[f * 128 + q];              dst = froff(q, f, 3); }
    else if (id < 126976)  { int li = id - 12288; int n = li >> 14; int r = li & 16383;
                             int q = r >> 7, f = r & 127;
                             v = Wsa[n * 16384 + f * 128 + q]; dst = 12288 + n * 16384 + froff(q, f, 4); }
    else if (id < 143360)  { int li = id - 126976; int q = li >> 7, f = li & 127;
                             v = Wq_[f * 128 + q];             dst = 126976 + froff(q, f, 4); }
    else if (id < 159744)  { int li = id - 143360; int q = li >> 7, f = li & 127;
                             v = Wk_[f * 128 + q];             dst = 143360 + froff(q, f, 4); }
    else if (id < 176128)  { int li = id - 159744; int q = li >> 7, f = li & 127;
                             v = Wv_[f * 128 + q];             dst = 159744 + froff(q, f, 4); }
    else if (id < 192512)  { int li = id - 176128; int q = li >> 7, f = li & 127;
                             v = Wo_[f * 128 + q];             dst = 176128 + froff(q, f, 4); }
    else if (id < 225280)  { int li = id - 192512; int q = li >> 8, f = li & 255;
                             v = W1[f * 128 + q];              dst = 192512 + froff(q, f, 8); }
    else                   { int li = id - 225280; int q = li >> 7, f = li & 127;
                             v = W2[f * 32 + q];               dst = 225280 + froff(q, f, 4); }
    o[dst] = f2bf(v);
}

__global__ void __launch_bounds__(256, 2)
ac_mfma(const float* __restrict__ s, const float* __restrict__ a,
        const unsigned short* __restrict__ WS,
        const float* __restrict__ b_enc_s, const float* __restrict__ b_enc_sa,
        const float* __restrict__ bv, const float* __restrict__ bo,
        const float* __restrict__ b_fc1, const float* __restrict__ b_fc2,
        float* __restrict__ out_q, float* __restrict__ out_allq)
{
    // 5 x 8704B buffers = 43,520 B
    __shared__ __align__(16) unsigned short SMEM[5 * TRB * PITCH];
    unsigned short* bufA0 = SMEM;                     // staging even-parity / attn / h1
    unsigned short* bufA1 = SMEM + TRB * PITCH;       // staging odd-parity ; P-overlay
    unsigned short* sE0   = SMEM + 2 * TRB * PITCH;   // e(even) / ov ; P-overlay
    unsigned short* sE1   = SMEM + 3 * TRB * PITCH;   // e(odd)
    unsigned short* sENC  = SMEM + 4 * TRB * PITCH;   // s_enc ; S-overlay

    const int t = threadIdx.x, lane = t & 63, wid = t >> 6;
    const int l15 = lane & 15, l4 = lane >> 4;
    const int M0 = 32 * wid;
    const int row0 = blockIdx.x * TRB;
    const float rsd = 0.17677669529663687f;  // 1/sqrt(32)

    const unsigned short* WencST = WS;
    const unsigned short* WsaT   = WS + 12288;
    const unsigned short* WqT    = WS + 126976;
    const unsigned short* WkT    = WS + 143360;
    const unsigned short* WvT    = WS + 159744;
    const unsigned short* WoT    = WS + 176128;
    const unsigned short* W1T    = WS + 192512;
    const unsigned short* W2T    = WS + 225280;

    f32x4 sf[3]; f32x4 af;

    // ---- prologue: stage s_i -> bufA0 ----
    ld_sa_f(s, a, row0, -1, t, sf, af);
    st_sa(bufA0, t, sf, af);
    __syncthreads();                            // P1

    // ---- s_enc = lrelu(s_i @ Wenc_s + b) ----
    f32x4 acc[2][2];
#pragma unroll
    for (int mt = 0; mt < 2; ++mt)
#pragma unroll
        for (int nt = 0; nt < 2; ++nt) acc[mt][nt] = (f32x4){0.f, 0.f, 0.f, 0.f};
    mmG<3>(WencST, 3, M0, 0, bufA0, lane, acc);
    ld_sa_f(s, a, row0, 0, t, sf, af);          // issue agent-0 staging loads
    __syncthreads();                            // P2: enc reads of bufA0 done
#pragma unroll
    for (int mt = 0; mt < 2; ++mt) {
        float4 bb = *(const float4*)(b_enc_s + M0 + mt * 16 + l4 * 4);
#pragma unroll
        for (int nt = 0; nt < 2; ++nt) {
            f32x4 v;
            v[0] = lrelu(acc[mt][nt][0] + bb.x); v[1] = lrelu(acc[mt][nt][1] + bb.y);
            v[2] = lrelu(acc[mt][nt][2] + bb.z); v[3] = lrelu(acc[mt][nt][3] + bb.w);
            *(ushort4*)(sENC + (nt * 16 + l15) * PITCH + M0 + mt * 16 + l4 * 4) = pack4v(v);
        }
    }
    st_sa(bufA1, t, sf, af);                    // staging(0) -> bufA1
    __syncthreads();                            // P3: sENC + staging(0) visible

    // ---- Q (register-resident; wave wid == head wid) ----
    f32x4 q[2][2];
#pragma unroll
    for (int mt = 0; mt < 2; ++mt)
#pragma unroll
        for (int nt = 0; nt < 2; ++nt) q[mt][nt] = (f32x4){0.f, 0.f, 0.f, 0.f};
    mmG<4>(WqT, 4, M0, 0, sENC, lane, q);

    // ---- hoist Wk/Wv fragments for the whole agent loop (64 regs) ----
    bf16x8 WkF[2][4], WvF[2][4];
    ldW<4>(WkT, 4, M0, 0, lane, WkF);
    ldW<4>(WvT, 4, M0, 0, lane, WvF);

    float4 bvf[2];
#pragma unroll
    for (int mt = 0; mt < 2; ++mt) bvf[mt] = *(const float4*)(bv + M0 + mt * 16 + l4 * 4);

    f32x4 atn[2][2];
#pragma unroll
    for (int mt = 0; mt < 2; ++mt)
#pragma unroll
        for (int nt = 0; nt < 2; ++nt) atn[mt][nt] = (f32x4){0.f, 0.f, 0.f, 0.f};
    float m_[2] = {-INFINITY, -INFINITY}, l_[2] = {0.f, 0.f};

    // merged K+V + online-softmax for one e-tile (frags in regs; single LDS pass)
    auto kv_phase = [&](const unsigned short* EB){
        f32x4 kk[2][2], vv[2][2];
#pragma unroll
        for (int mt = 0; mt < 2; ++mt)
#pragma unroll
            for (int nt = 0; nt < 2; ++nt) {
                kk[mt][nt] = (f32x4){0.f, 0.f, 0.f, 0.f};
                vv[mt][nt] = (f32x4){0.f, 0.f, 0.f, 0.f};
            }
        __builtin_amdgcn_s_setprio(1);
#pragma unroll
        for (int kc = 0; kc < 4; ++kc) {
            bf16x8 b[2];
#pragma unroll
            for (int nt = 0; nt < 2; ++nt) b[nt] = ldB(EB, nt * 16, kc, lane);
#pragma unroll
            for (int mt = 0; mt < 2; ++mt)
#pragma unroll
                for (int nt = 0; nt < 2; ++nt) {
                    kk[mt][nt] = __builtin_amdgcn_mfma_f32_16x16x32_bf16(WkF[mt][kc], b[nt], kk[mt][nt], 0, 0, 0);
                    vv[mt][nt] = __builtin_amdgcn_mfma_f32_16x16x32_bf16(WvF[mt][kc], b[nt], vv[mt][nt], 0, 0, 0);
                }
        }
        __builtin_amdgcn_s_setprio(0);
        float pr[2], corr[2];
#pragma unroll
        for (int nt = 0; nt < 2; ++nt) {
            float p = 0.f;
#pragma unroll
            for (int mt = 0; mt < 2; ++mt)
#pragma unroll
                for (int r = 0; r < 4; ++r) p = fmaf(q[mt][nt][r], kk[mt][nt][r], p);
            p += __shfl_xor(p, 16);
            p += __shfl_xor(p, 32);
            float sc = p * rsd;
            float mo = m_[nt], mn = fmaxf(mo, sc);
            pr[nt]   = __expf(sc - mn);
            corr[nt] = __expf(mo - mn);
            l_[nt] = l_[nt] * corr[nt] + pr[nt];
            m_[nt] = mn;
        }
#pragma unroll
        for (int mt = 0; mt < 2; ++mt)
#pragma unroll
            for (int nt = 0; nt < 2; ++nt)
#pragma unroll
                for (int r = 0; r < 4; ++r) {
                    float vx = lrelu(vv[mt][nt][r] + ((const float*)&bvf[mt])[r]);
                    atn[mt][nt][r] = fmaf(atn[mt][nt][r], corr[nt], pr[nt] * vx);
                }
    };

    // ---- agent loop: ONE barrier per iteration ----
    for (int n = 0; n < 7; ++n) {
        unsigned short* stageRd = (n & 1) ? bufA0 : bufA1;
        unsigned short* stageWr = (n & 1) ? bufA1 : bufA0;
        unsigned short* eWr     = (n & 1) ? sE1 : sE0;
        unsigned short* eRd     = (n & 1) ? sE0 : sE1;

        if (n < 6) ld_sa_f(s, a, row0, n + 1, t, sf, af);   // issue nt loads early
        bf16x8 F[2][4];
        ldW<4>(WsaT + n * 16384, 4, M0, 0, lane, F);        // issue Wsa(n) frags

        if (n) kv_phase(eRd);                               // KV(n-1) under the loads

        f32x4 e[2][2];
#pragma unroll
        for (int mt = 0; mt < 2; ++mt)
#pragma unroll
            for (int nt = 0; nt < 2; ++nt) e[mt][nt] = (f32x4){0.f, 0.f, 0.f, 0.f};
        mmR<4>(F, stageRd, lane, e);

#pragma unroll
        for (int mt = 0; mt < 2; ++mt) {
            float4 bb = *(const float4*)(b_enc_sa + n * 128 + M0 + mt * 16 + l4 * 4);
#pragma unroll
            for (int nt = 0; nt < 2; ++nt) {
                f32x4 v;
                v[0] = lrelu(e[mt][nt][0] + bb.x); v[1] = lrelu(e[mt][nt][1] + bb.y);
                v[2] = lrelu(e[mt][nt][2] + bb.z); v[3] = lrelu(e[mt][nt][3] + bb.w);
                *(ushort4*)(eWr + (nt * 16 + l15) * PITCH + M0 + mt * 16 + l4 * 4) = pack4v(v);
            }
        }
        if (n < 6) st_sa(stageWr, t, sf, af);
        __syncthreads();                        // the one barrier
    }
    kv_phase(sE0);                              // agent 6 (e(6) is in sE0)

    // ---- epilogue pipelining: prefetch Wo frags; h1 half-1 from sENC (stable) ----
    bf16x8 WoF[2][4];
    ldW<4>(WoT, 4, M0, 0, lane, WoF);
    f32x4 hacc[2][2];
#pragma unroll
    for (int mt = 0; mt < 2; ++mt)
#pragma unroll
        for (int nt = 0; nt < 2; ++nt) hacc[mt][nt] = (f32x4){0.f, 0.f, 0.f, 0.f};
    mmG<4>(W1T, 8, M0, 0, sENC, lane, hacc);    // h1 k=0..127 (overlaps E1 region)

    // ---- attn normalize -> bufA0 ----
#pragma unroll
    for (int mt = 0; mt < 2; ++mt)
#pragma unroll
        for (int nt = 0; nt < 2; ++nt) {
            float inv = 1.f / l_[nt];
            f32x4 v;
            v[0] = atn[mt][nt][0] * inv; v[1] = atn[mt][nt][1] * inv;
            v[2] = atn[mt][nt][2] * inv; v[3] = atn[mt][nt][3] * inv;
            *(ushort4*)(bufA0 + (nt * 16 + l15) * PITCH + M0 + mt * 16 + l4 * 4) = pack4v(v);
        }
    __syncthreads();                            // E1

    // ---- prefetch W1 half-2 frags; ov = attn @ Wo + bo -> sE0 ----
    bf16x8 W1F[2][4];
    ldW<4>(W1T, 8, M0, 4, lane, W1F);
#pragma unroll
    for (int mt = 0; mt < 2; ++mt)
#pragma unroll
        for (int nt = 0; nt < 2; ++nt) acc[mt][nt] = (f32x4){0.f, 0.f, 0.f, 0.f};
    mmR<4>(WoF, bufA0, lane, acc);
#pragma unroll
    for (int mt = 0; mt < 2; ++mt) {
        float4 bb = *(const float4*)(bo + M0 + mt * 16 + l4 * 4);
#pragma unroll
        for (int nt = 0; nt < 2; ++nt) {
            f32x4 v;
            v[0] = acc[mt][nt][0] + bb.x; v[1] = acc[mt][nt][1] + bb.y;
            v[2] = acc[mt][nt][2] + bb.z; v[3] = acc[mt][nt][3] + bb.w;
            *(ushort4*)(sE0 + (nt * 16 + l15) * PITCH + M0 + mt * 16 + l4 * 4) = pack4v(v);
        }
    }
    __syncthreads();                            // E2

    // ---- h1 half-2 (ov in sE0, frags prefetched) -> bufA0 ----
    mmR<4>(W1F, sE0, lane, hacc);
    // prefetch fc2 fragments (used after E4)
    bf16x8 a0 = ldA(W2T, 4, 0, wid, lane);
    bf16x8 a1 = ldA(W2T, 4, 16, wid, lane);
#pragma unroll
    for (int mt = 0; mt < 2; ++mt) {
        float4 bb = *(const float4*)(b_fc1 + M0 + mt * 16 + l4 * 4);
#pragma unroll
        for (int nt = 0; nt < 2; ++nt) {
            f32x4 v;
            v[0] = lrelu(hacc[mt][nt][0] + bb.x); v[1] = lrelu(hacc[mt][nt][1] + bb.y);
            v[2] = lrelu(hacc[mt][nt][2] + bb.z); v[3] = lrelu(hacc[mt][nt][3] + bb.w);
            *(ushort4*)(bufA0 + (nt * 16 + l15) * PITCH + M0 + mt * 16 + l4 * 4) = pack4v(v);
        }
    }
    __syncthreads();                            // E4: h1 visible

    // ---- all_q = h1 @ W_fc2 + b2 : wave wid takes K-chunk kc=wid ----
    float* P = (float*)(SMEM + TRB * PITCH);    // 16KB overlay on bufA1+sE0 (dead)
    {
        bf16x8 b0 = ldB(bufA0, 0, wid, lane);
        bf16x8 b1 = ldB(bufA0, 16, wid, lane);
        f32x4 z = (f32x4){0.f, 0.f, 0.f, 0.f};
        f32x4 c00 = __builtin_amdgcn_mfma_f32_16x16x32_bf16(a0, b0, z, 0, 0, 0);
        f32x4 c01 = __builtin_amdgcn_mfma_f32_16x16x32_bf16(a0, b1, z, 0, 0, 0);
        f32x4 c10 = __builtin_amdgcn_mfma_f32_16x16x32_bf16(a1, b0, z, 0, 0, 0);
        f32x4 c11 = __builtin_amdgcn_mfma_f32_16x16x32_bf16(a1, b1, z, 0, 0, 0);
        *(f32x4*)(P + wid * 1024 + (l15     ) * 32 +      l4 * 4) = c00;
        *(f32x4*)(P + wid * 1024 + (16 + l15) * 32 +      l4 * 4) = c01;
        *(f32x4*)(P + wid * 1024 + (l15     ) * 32 + 16 + l4 * 4) = c10;
        *(f32x4*)(P + wid * 1024 + (16 + l15) * 32 + 16 + l4 * 4) = c11;
    }
    __syncthreads();                            // E5

    float* S = (float*)sENC;                    // stash [32][33] overlay (sENC dead)
#pragma unroll
    for (int j = 0; j < 4; ++j) {
        int o = t + 256 * j; int row = o >> 5, f = o & 31;
        float v = P[row * 32 + f] + P[1024 + row * 32 + f]
                + P[2048 + row * 32 + f] + P[3072 + row * 32 + f] + b_fc2[f];
        out_allq[(size_t)(row0 + row) * 32 + f] = v;
        S[row * 33 + f] = v;
    }
    __syncthreads();                            // E6

    // ---- q = all_q[argmax(a[:, :32])] ----
    if (t < TRB) {
        int row = row0 + t;
        float best = -INFINITY; int bi = 0;
#pragma unroll
        for (int jj = 0; jj < 8; ++jj) {
            f32x4 v = ldg_nt4(a + (size_t)row * 256 + jj * 4);
#pragma unroll
            for (int e2 = 0; e2 < 4; ++e2)
                if (v[e2] > best) { best = v[e2]; bi = jj * 4 + e2; }
        }
        out_q[row] = S[t * 33 + bi];
    }
}

extern "C" void kernel_launch(void* const* d_in, const int* in_sizes, int n_in,
                              void* d_out, int out_size, void* d_ws, size_t ws_size,
                              hipStream_t stream)
{
    (void)n_in; (void)out_size; (void)ws_size;
    const float* s        = (const float*)d_in[0];
    const float* a        = (const float*)d_in[1];
    const float* W_enc_s  = (const float*)d_in[2];
    const float* b_enc_s  = (const float*)d_in[3];
    const float* W_enc_sa = (const float*)d_in[4];
    const float* b_enc_sa = (const float*)d_in[5];
    const float* Wq       = (const float*)d_in[6];
    const float* Wk       = (const float*)d_in[7];
    const float* Wv       = (const float*)d_in[8];
    const float* bv       = (const float*)d_in[9];
    const float* Wo       = (const float*)d_in[10];
    const float* bo       = (const float*)d_in[11];
    const float* W_fc1    = (const float*)d_in[12];
    const float* b_fc1    = (const float*)d_in[13];
    const float* W_fc2    = (const float*)d_in[14];
    const float* b_fc2    = (const float*)d_in[15];

    int B = in_sizes[0] / 768;
    float* out_q    = (float*)d_out;
    float* out_allq = out_q + B;
    unsigned short* WS = (unsigned short*)d_ws;

    wprep<<<dim3(896), dim3(256), 0, stream>>>(W_enc_s, W_enc_sa, Wq, Wk, Wv, Wo,
                                               W_fc1, W_fc2, WS);
    ac_mfma<<<dim3(B / TRB), dim3(256), 0, stream>>>(s, a, WS, b_enc_s, b_enc_sa,
                                                     bv, bo, b_fc1, b_fc2,
                                                     out_q, out_allq);
}